// Round 15
// baseline (306.628 us; speedup 1.0000x reference)
//
#include <hip/hip_runtime.h>
#include <math.h>

#define DEVINL __device__ __forceinline__

DEVINL float sigm(float x) { return 1.0f / (1.0f + __expf(-x)); }
DEVINL float tanh_fast(float x) { return 2.0f / (1.0f + __expf(-2.0f * x)) - 1.0f; }
DEVINL unsigned short bf16rne(float f) {
    unsigned u = __float_as_uint(f);
    return (unsigned short)((u + 0x7FFFu + ((u >> 16) & 1u)) >> 16);
}

typedef __attribute__((ext_vector_type(8))) short bf16x8;
typedef __attribute__((ext_vector_type(4))) float f32x4;

// ---------------------------------------------------------------------------
// Generic small GEMM, K-unrolled x4 (R11-verified)
// ---------------------------------------------------------------------------
__global__ void gemm_small(const float* __restrict__ A, const float* __restrict__ W,
                           const float* __restrict__ bias, float* __restrict__ C,
                           int M, int N, int K, int act, int vgroup)
{
    int idx = blockIdx.x * blockDim.x + threadIdx.x;
    if (idx >= M * N) return;
    int m = idx / N, n = idx - m * N;
    int am = m;
    if (vgroup) { int g = m / vgroup; am = g * (vgroup + 1) + (m - g * vgroup); }
    const float* a = A + (size_t)am * K;
    const float* w = W + n;
    float acc = bias ? bias[n] : 0.0f;
    for (int k = 0; k < K; k += 4) {
        float4 av = *(const float4*)&a[k];
        float w0 = w[(size_t)k * N];
        float w1 = w[(size_t)(k + 1) * N];
        float w2 = w[(size_t)(k + 2) * N];
        float w3 = w[(size_t)(k + 3) * N];
        acc = fmaf(av.x, w0, acc);
        acc = fmaf(av.y, w1, acc);
        acc = fmaf(av.z, w2, acc);
        acc = fmaf(av.w, w3, acc);
    }
    if (act == 1) acc = fmaxf(acc, 0.0f);
    else if (act == 2) acc = tanh_fast(acc);
    C[idx] = acc;
}

// ---------------------------------------------------------------------------
// Dual-output small GEMM (R12-verified): C1 = A@W1, C2 = A@W2, A read once.
// ---------------------------------------------------------------------------
__global__ void gemm_small_dual(const float* __restrict__ A,
    const float* __restrict__ W1, const float* __restrict__ W2,
    float* __restrict__ C1, float* __restrict__ C2, int M, int N, int K)
{
    int idx = blockIdx.x * blockDim.x + threadIdx.x;
    if (idx >= M * N) return;
    int m = idx / N, n = idx - m * N;
    const float* a = A + (size_t)m * K;
    const float* w1 = W1 + n;
    const float* w2 = W2 + n;
    float acc1 = 0.0f, acc2 = 0.0f;
    for (int k = 0; k < K; k += 4) {
        float4 av = *(const float4*)&a[k];
        float p0 = w1[(size_t)k * N],       q0 = w2[(size_t)k * N];
        float p1 = w1[(size_t)(k + 1) * N], q1 = w2[(size_t)(k + 1) * N];
        float p2 = w1[(size_t)(k + 2) * N], q2 = w2[(size_t)(k + 2) * N];
        float p3 = w1[(size_t)(k + 3) * N], q3 = w2[(size_t)(k + 3) * N];
        acc1 = fmaf(av.x, p0, acc1); acc2 = fmaf(av.x, q0, acc2);
        acc1 = fmaf(av.y, p1, acc1); acc2 = fmaf(av.y, q1, acc2);
        acc1 = fmaf(av.z, p2, acc1); acc2 = fmaf(av.z, q2, acc2);
        acc1 = fmaf(av.w, p3, acc1); acc2 = fmaf(av.w, q3, acc2);
    }
    C1[idx] = acc1;
    C2[idx] = acc2;
}

// ---------------------------------------------------------------------------
// Wave-parallel GRU (R6-verified)
// ---------------------------------------------------------------------------
__global__ __launch_bounds__(256) void gru_wave(const float* __restrict__ glu,
    const float* __restrict__ timev, const float* __restrict__ Wx,
    const float* __restrict__ Wh, const float* __restrict__ bb,
    float* __restrict__ out)
{
    __shared__ float sWh[768], sWx[96], sb[48];
    int tid = threadIdx.x;
    for (int i = tid; i < 768; i += 256) sWh[i] = Wh[i];
    if (tid < 96) sWx[tid] = Wx[tid];
    if (tid < 48) sb[tid] = bb[tid];
    __syncthreads();
    int j = tid & 15;
    int seq = blockIdx.x * 16 + (tid >> 4);
    int gbase = (tid & 63) & 0x30;
    float whz[16], whr[16], whn[16];
#pragma unroll
    for (int i = 0; i < 16; ++i) {
        whz[i] = sWh[i * 48 + j];
        whr[i] = sWh[i * 48 + 16 + j];
        whn[i] = sWh[i * 48 + 32 + j];
    }
    float wxz0 = sWx[j],      wxr0 = sWx[16 + j], wxn0 = sWx[32 + j];
    float wxz1 = sWx[48 + j], wxr1 = sWx[64 + j], wxn1 = sWx[80 + j];
    float bz = sb[j], br = sb[16 + j], bn = sb[32 + j];
    const float* gp = glu + (size_t)seq * 48;
    const float* tp = timev + (size_t)seq * 48;
    float h = 0.0f;
    for (int t = 0; t < 48; ++t) {
        float gl = gp[t], tm = tp[t];
        float gz = fmaf(gl, wxz0, fmaf(tm, wxz1, bz));
        float gr = fmaf(gl, wxr0, fmaf(tm, wxr1, br));
        float gn = fmaf(gl, wxn0, fmaf(tm, wxn1, bn));
        float ghn = 0.0f;
#pragma unroll
        for (int i = 0; i < 16; ++i) {
            float hb = __shfl(h, gbase + i, 64);
            gz = fmaf(hb, whz[i], gz);
            gr = fmaf(hb, whr[i], gr);
            ghn = fmaf(hb, whn[i], ghn);
        }
        float z = sigm(gz), r = sigm(gr);
        float n = tanh_fast(gn + r * ghn);
        h = (1.0f - z) * n + z * h;
    }
    out[(size_t)seq * 16 + j] = h;
}

// ---------------------------------------------------------------------------
// glu attn_enc (per batch) -> patient_rep with static concat
// ---------------------------------------------------------------------------
__global__ __launch_bounds__(256) void glu_attn(const float* __restrict__ hg,
    const float* __restrict__ Wq, const float* __restrict__ Wk,
    const float* __restrict__ s2, float* __restrict__ patient)
{
    int b = blockIdx.x, tid = threadIdx.x;
    __shared__ float sh[512], sq[256], sk[256], ss[256];
    sh[tid] = hg[(size_t)b * 512 + tid];
    sh[256 + tid] = hg[(size_t)b * 512 + 256 + tid];
    __syncthreads();
    {
        int p = tid >> 4, j = tid & 15;
        float aq = 0.0f, ak = 0.0f;
        for (int i = 0; i < 32; ++i) {
            float hv = sh[p * 32 + i];
            aq = fmaf(hv, Wq[i * 16 + j], aq);
            ak = fmaf(hv, Wk[i * 16 + j], ak);
        }
        sq[tid] = aq; sk[tid] = ak;
    }
    __syncthreads();
    {
        int p = tid >> 4, pk = tid & 15;
        float a = 0.0f;
        for (int j = 0; j < 16; ++j) a = fmaf(sq[p * 16 + j], sk[pk * 16 + j], a);
        ss[tid] = a * 0.25f;
    }
    __syncthreads();
    if (tid < 16) {
        float mx = -1e30f;
        for (int k = 0; k < 16; ++k) mx = fmaxf(mx, ss[tid * 16 + k]);
        float sum = 0.0f;
        for (int k = 0; k < 16; ++k) { float e = __expf(ss[tid * 16 + k] - mx); ss[tid * 16 + k] = e; sum += e; }
        float inv = 1.0f / sum;
        for (int k = 0; k < 16; ++k) ss[tid * 16 + k] *= inv;
    }
    __syncthreads();
    for (int o = tid; o < 512; o += 256) {
        int p = o >> 5, c = o & 31;
        float acc = 0.0f;
        for (int pk = 0; pk < 16; ++pk) acc = fmaf(ss[p * 16 + pk], sh[pk * 32 + c], acc);
        patient[((size_t)b * 16 + p) * 64 + c] = acc;
        patient[((size_t)b * 16 + p) * 64 + 32 + c] = s2[(size_t)b * 32 + c];
    }
}

// ---------------------------------------------------------------------------
// med attn_enc (per batch)
// ---------------------------------------------------------------------------
__global__ __launch_bounds__(256) void med_attn(const float* __restrict__ hm,
    const float* __restrict__ Wq, const float* __restrict__ Wk,
    float* __restrict__ med_rep)
{
    int b = blockIdx.x, tid = threadIdx.x;
    __shared__ float sh[960], sq[480], sk[480], ss[225];
    for (int i = tid; i < 960; i += 256) sh[i] = hm[(size_t)b * 960 + i];
    __syncthreads();
    for (int o = tid; o < 480; o += 256) {
        int p = o >> 5, j = o & 31;
        float aq = 0.0f, ak = 0.0f;
        for (int i = 0; i < 64; ++i) {
            float hv = sh[p * 64 + i];
            aq = fmaf(hv, Wq[i * 32 + j], aq);
            ak = fmaf(hv, Wk[i * 32 + j], ak);
        }
        sq[o] = aq; sk[o] = ak;
    }
    __syncthreads();
    if (tid < 225) {
        int p = tid / 15, pk = tid - p * 15;
        float a = 0.0f;
        for (int j = 0; j < 32; ++j) a = fmaf(sq[p * 32 + j], sk[pk * 32 + j], a);
        ss[tid] = a * 0.17677669529663687f;
    }
    __syncthreads();
    if (tid < 15) {
        float mx = -1e30f;
        for (int k = 0; k < 15; ++k) mx = fmaxf(mx, ss[tid * 15 + k]);
        float sum = 0.0f;
        for (int k = 0; k < 15; ++k) { float e = __expf(ss[tid * 15 + k] - mx); ss[tid * 15 + k] = e; sum += e; }
        float inv = 1.0f / sum;
        for (int k = 0; k < 15; ++k) ss[tid * 15 + k] *= inv;
    }
    __syncthreads();
    for (int o = tid; o < 960; o += 256) {
        int p = o >> 6, c = o & 63;
        float acc = 0.0f;
        for (int pk = 0; pk < 15; ++pk) acc = fmaf(ss[p * 15 + pk], sh[pk * 64 + c], acc);
        med_rep[(size_t)b * 960 + o] = acc;
    }
}

// ---------------------------------------------------------------------------
// drug_mem[192,64]
// ---------------------------------------------------------------------------
__global__ void drugmem_kernel(const float* __restrict__ ehr, const float* __restrict__ tadj,
    const float* __restrict__ ddi,
    const float* __restrict__ Wl1, const float* __restrict__ bl1,
    const float* __restrict__ Wl2, const float* __restrict__ bl2,
    const float* __restrict__ Wl3, const float* __restrict__ bl3,
    float* __restrict__ dm)
{
    int idx = blockIdx.x * 256 + threadIdx.x;
    if (idx >= 192 * 64) return;
    int m = idx >> 6, n = idx & 63;
    float acc = bl1[n] + bl2[n] - bl3[n];
    for (int k = 0; k < 192; ++k) {
        acc = fmaf(ehr[m * 192 + k], Wl1[k * 64 + n], acc);
        acc = fmaf(tadj[m * 192 + k], Wl2[k * 64 + n], acc);
        acc = fmaf(-ddi[m * 192 + k], Wl3[k * 64 + n], acc);
    }
    dm[idx] = acc;
}

// ---------------------------------------------------------------------------
// MHA-1 (per batch). sq/sk padded to stride 68.
// ---------------------------------------------------------------------------
__global__ __launch_bounds__(256) void mha1_attn(const float* __restrict__ qh1,
    const float* __restrict__ kh1, const float* __restrict__ vh1,
    const float* __restrict__ Wo, float* __restrict__ Een)
{
    int b = blockIdx.x, tid = threadIdx.x;
    __shared__ float sq[1020], sk[1088], sv[1024], ss[960], so[960];
    for (int i = tid; i < 960; i += 256) sq[(i >> 6) * 68 + (i & 63)] = qh1[(size_t)b * 960 + i];
    for (int i = tid; i < 1024; i += 256) {
        sk[(i >> 6) * 68 + (i & 63)] = kh1[(size_t)b * 1024 + i];
        sv[i] = vh1[(size_t)b * 1024 + i];
    }
    __syncthreads();
    for (int o = tid; o < 960; o += 256) {
        int hh = o / 240, rem = o - hh * 240, q = rem >> 4, k = rem & 15;
        float a = 0.0f;
        for (int d = 0; d < 16; ++d) a = fmaf(sq[q * 68 + hh * 16 + d], sk[k * 68 + hh * 16 + d], a);
        ss[o] = a * 0.25f;
    }
    __syncthreads();
    if (tid < 60) {
        int base = tid * 16;
        float mx = -1e30f;
        for (int k = 0; k < 16; ++k) mx = fmaxf(mx, ss[base + k]);
        float sum = 0.0f;
        for (int k = 0; k < 16; ++k) { float e = __expf(ss[base + k] - mx); ss[base + k] = e; sum += e; }
        float inv = 1.0f / sum;
        for (int k = 0; k < 16; ++k) ss[base + k] *= inv;
    }
    __syncthreads();
    for (int o = tid; o < 960; o += 256) {
        int q = o >> 6, j = o & 63, hh = j >> 4;
        float a = 0.0f;
        for (int k = 0; k < 16; ++k) a = fmaf(ss[hh * 240 + q * 16 + k], sv[k * 64 + j], a);
        so[o] = a;
    }
    __syncthreads();
    for (int o = tid; o < 960; o += 256) {
        int q = o >> 6, c = o & 63;
        float a = 0.0f;
        for (int j = 0; j < 64; ++j) a = fmaf(so[q * 64 + j], Wo[j * 64 + c], a);
        Een[(size_t)b * 960 + o] = a;
    }
}

// ---------------------------------------------------------------------------
// MHA-2 v2 (R8-verified): block per (batch, q-chunk); stride-68 K; no Wo.
// ---------------------------------------------------------------------------
__global__ __launch_bounds__(256) void mha2_attn2(const float* __restrict__ qh2,
    const float* __restrict__ kh2, const float* __restrict__ vh2,
    float* __restrict__ so_all)
{
    int b = blockIdx.x >> 2, q0 = (blockIdx.x & 3) * 48;
    int tid = threadIdx.x;
    __shared__ float skp[1020], sv[960], ss[2880];
    for (int i = tid; i < 960; i += 256) {
        skp[(i >> 6) * 68 + (i & 63)] = kh2[(size_t)b * 960 + i];
        sv[i] = vh2[(size_t)b * 960 + i];
    }
    __syncthreads();
    for (int o = tid; o < 2880; o += 256) {
        int hh = o / 720, rem = o - hh * 720, q = rem / 15, k = rem - q * 15;
        const float* qp = qh2 + (size_t)(q0 + q) * 64 + hh * 16;
        float a = 0.0f;
        for (int d = 0; d < 16; ++d) a = fmaf(qp[d], skp[k * 68 + hh * 16 + d], a);
        ss[o] = a * 0.25f;
    }
    __syncthreads();
    if (tid < 192) {
        int hh = tid / 48, q = tid - hh * 48;
        int base = hh * 720 + q * 15;
        float mx = -1e30f;
        for (int k = 0; k < 15; ++k) mx = fmaxf(mx, ss[base + k]);
        float sum = 0.0f;
        for (int k = 0; k < 15; ++k) { float e = __expf(ss[base + k] - mx); ss[base + k] = e; sum += e; }
        float inv = 1.0f / sum;
        for (int k = 0; k < 15; ++k) ss[base + k] *= inv;
    }
    __syncthreads();
    for (int o = tid; o < 3072; o += 256) {
        int q = o >> 6, j = o & 63, hh = j >> 4;
        float a = 0.0f;
        for (int k = 0; k < 15; ++k) a = fmaf(ss[hh * 720 + q * 15 + k], sv[k * 64 + j], a);
        so_all[((size_t)b * 192 + q0 + q) * 64 + j] = a;
    }
}

// ---------------------------------------------------------------------------
// Abf = bf16(relu(so[98304,64] @ Wo[64,64])), f32 math, fused epilogue.
// ---------------------------------------------------------------------------
__global__ __launch_bounds__(256) void gemm64_relu_bf16(const float* __restrict__ A,
    const float* __restrict__ B, unsigned short* __restrict__ Obf)
{
    __shared__ float As[64 * 20];
    __shared__ float Bs[16 * 64];
    int tid = threadIdx.x;
    int m0 = blockIdx.x * 64;
    float acc[4][4] = {};
    int arow = tid >> 2, akq = (tid & 3) << 2;
    int brow = tid >> 4, bnq = (tid & 15) << 2;
    int tm0 = (tid >> 4) << 2, tn0 = (tid & 15) << 2;
    for (int kt = 0; kt < 64; kt += 16) {
        float4 av = *(const float4*)&A[(size_t)(m0 + arow) * 64 + kt + akq];
        *(float4*)&As[arow * 20 + akq] = av;
        float4 bv = *(const float4*)&B[(size_t)(kt + brow) * 64 + bnq];
        *(float4*)&Bs[brow * 64 + bnq] = bv;
        __syncthreads();
#pragma unroll
        for (int kk = 0; kk < 16; ++kk) {
            float4 b4 = *(const float4*)&Bs[kk * 64 + tn0];
            float a0 = As[(tm0 + 0) * 20 + kk];
            float a1 = As[(tm0 + 1) * 20 + kk];
            float a2 = As[(tm0 + 2) * 20 + kk];
            float a3 = As[(tm0 + 3) * 20 + kk];
            acc[0][0] = fmaf(a0, b4.x, acc[0][0]); acc[0][1] = fmaf(a0, b4.y, acc[0][1]);
            acc[0][2] = fmaf(a0, b4.z, acc[0][2]); acc[0][3] = fmaf(a0, b4.w, acc[0][3]);
            acc[1][0] = fmaf(a1, b4.x, acc[1][0]); acc[1][1] = fmaf(a1, b4.y, acc[1][1]);
            acc[1][2] = fmaf(a1, b4.z, acc[1][2]); acc[1][3] = fmaf(a1, b4.w, acc[1][3]);
            acc[2][0] = fmaf(a2, b4.x, acc[2][0]); acc[2][1] = fmaf(a2, b4.y, acc[2][1]);
            acc[2][2] = fmaf(a2, b4.z, acc[2][2]); acc[2][3] = fmaf(a2, b4.w, acc[2][3]);
            acc[3][0] = fmaf(a3, b4.x, acc[3][0]); acc[3][1] = fmaf(a3, b4.y, acc[3][1]);
            acc[3][2] = fmaf(a3, b4.z, acc[3][2]); acc[3][3] = fmaf(a3, b4.w, acc[3][3]);
        }
        __syncthreads();
    }
#pragma unroll
    for (int i = 0; i < 4; ++i) {
        unsigned r0 = (unsigned)bf16rne(fmaxf(acc[i][0], 0.f)) | ((unsigned)bf16rne(fmaxf(acc[i][1], 0.f)) << 16);
        unsigned r1 = (unsigned)bf16rne(fmaxf(acc[i][2], 0.f)) | ((unsigned)bf16rne(fmaxf(acc[i][3], 0.f)) << 16);
        uint2 v = { r0, r1 };
        *(uint2*)&Obf[(size_t)(m0 + tm0 + i) * 64 + tn0] = v;
    }
}

// ---------------------------------------------------------------------------
// MFMA bf16 split-K GEMM v4 (byte-identical resubmit of R14; R7->R8 protocol:
// abort with no found bug -> resubmit to split environmental vs genuine).
// R12 geometry (128x64, sk=8, conflict-free scalar B staging) + register
// prefetch of next K-tile (A: 4x uint4, B: 16 floats) issued after the
// stage-barrier so HBM latency hides under this tile's 16 MFMAs.
// ---------------------------------------------------------------------------
__global__ __launch_bounds__(256) void gemm_mfma_bf16(
    const unsigned short* __restrict__ Abf, const float* __restrict__ B,
    float* __restrict__ Cp, int M, int N, int K, int klen)
{
    __shared__ unsigned short As[128 * 64];   // 16 KB
    __shared__ unsigned short Bs[64 * 64];    // 8 KB
    int tid = threadIdx.x;
    int lane = tid & 63, w = tid >> 6;
    int n0 = blockIdx.x * 64, m0 = blockIdx.y * 128;
    int kbase0 = blockIdx.z * klen;
    f32x4 acc[2][4] = {};

    int bn = tid & 63, bkc = (tid >> 6) * 16;
    uint4 ar[4];
    float br[16];
    // prefetch tile 0
#pragma unroll
    for (int c = 0; c < 4; ++c) {
        int ch = tid + c * 256;
        int row = ch >> 3, kc0 = (ch & 7) << 3;
        ar[c] = *(const uint4*)&Abf[(size_t)(m0 + row) * K + kbase0 + kc0];
    }
    {
        const float* bp = &B[(size_t)(kbase0 + bkc) * N + n0 + bn];
#pragma unroll
        for (int j = 0; j < 16; ++j) br[j] = bp[(size_t)j * N];
    }
    for (int kt = 0; kt < klen; kt += 64) {
        int kb = kbase0 + kt;
        // write staged regs -> LDS
#pragma unroll
        for (int c = 0; c < 4; ++c) {
            int ch = tid + c * 256;
            int row = ch >> 3, kc0 = (ch & 7) << 3;
            int bo = ((row << 7) + (kc0 << 1)) ^ ((row & 7) << 4);
            *(uint4*)((char*)As + bo) = ar[c];
        }
#pragma unroll
        for (int j = 0; j < 16; j += 2) {
            unsigned u = (unsigned)bf16rne(br[j]) | ((unsigned)bf16rne(br[j + 1]) << 16);
            int k = bkc + j;
            int bo = ((bn << 7) + (k << 1)) ^ ((bn & 7) << 4);
            *(unsigned*)((char*)Bs + bo) = u;
        }
        __syncthreads();
        // prefetch next tile while this tile computes
        if (kt + 64 < klen) {
            int kn = kb + 64;
#pragma unroll
            for (int c = 0; c < 4; ++c) {
                int ch = tid + c * 256;
                int row = ch >> 3, kc0 = (ch & 7) << 3;
                ar[c] = *(const uint4*)&Abf[(size_t)(m0 + row) * K + kn + kc0];
            }
            const float* bp = &B[(size_t)(kn + bkc) * N + n0 + bn];
#pragma unroll
            for (int j = 0; j < 16; ++j) br[j] = bp[(size_t)j * N];
        }
#pragma unroll
        for (int kk = 0; kk < 64; kk += 32) {
            int kb2 = (kk + ((lane >> 4) << 3)) << 1;
            bf16x8 af[2], bfg[4];
#pragma unroll
            for (int fm = 0; fm < 2; ++fm) {
                int row = (w << 5) + (fm << 4) + (lane & 15);
                af[fm] = *(const bf16x8*)((const char*)As + (((row << 7) + kb2) ^ ((row & 7) << 4)));
            }
#pragma unroll
            for (int fn = 0; fn < 4; ++fn) {
                int col = (fn << 4) + (lane & 15);
                bfg[fn] = *(const bf16x8*)((const char*)Bs + (((col << 7) + kb2) ^ ((col & 7) << 4)));
            }
#pragma unroll
            for (int fm = 0; fm < 2; ++fm)
#pragma unroll
                for (int fn = 0; fn < 4; ++fn)
                    acc[fm][fn] = __builtin_amdgcn_mfma_f32_16x16x32_bf16(af[fm], bfg[fn], acc[fm][fn], 0, 0, 0);
        }
        __syncthreads();
    }
    float* cp = Cp + (size_t)blockIdx.z * M * N;
#pragma unroll
    for (int fm = 0; fm < 2; ++fm)
#pragma unroll
        for (int fn = 0; fn < 4; ++fn) {
            int row = m0 + (w << 5) + (fm << 4) + ((lane >> 4) << 2);
            int col = n0 + (fn << 4) + (lane & 15);
#pragma unroll
            for (int r = 0; r < 4; ++r)
                cp[(size_t)(row + r) * N + col] = acc[fm][fn][r];
        }
}

// ---------------------------------------------------------------------------
// Split-K tiled f32 GEMM
// ---------------------------------------------------------------------------
template <int RELU_A>
__global__ __launch_bounds__(256) void gemm_sk(const float* __restrict__ A,
    const float* __restrict__ B, float* __restrict__ Cp,
    int M, int N, int K, int klen)
{
    __shared__ float As[64 * 20];
    __shared__ float Bs[16 * 64];
    int tid = threadIdx.x;
    int n0 = blockIdx.x * 64, m0 = blockIdx.y * 64;
    int bs = blockIdx.z;
    int kbase0 = bs * klen;
    float acc[4][4] = {};
    int arow = tid >> 2, akq = (tid & 3) << 2;
    int brow = tid >> 4, bnq = (tid & 15) << 2;
    int tm0 = (tid >> 4) << 2, tn0 = (tid & 15) << 2;
    for (int kt = 0; kt < klen; kt += 16) {
        int kb = kbase0 + kt;
        float4 av = *(const float4*)&A[(size_t)(m0 + arow) * K + kb + akq];
        if (RELU_A) {
            av.x = fmaxf(av.x, 0.0f); av.y = fmaxf(av.y, 0.0f);
            av.z = fmaxf(av.z, 0.0f); av.w = fmaxf(av.w, 0.0f);
        }
        *(float4*)&As[arow * 20 + akq] = av;
        float4 bv = *(const float4*)&B[(size_t)(kb + brow) * N + n0 + bnq];
        *(float4*)&Bs[brow * 64 + bnq] = bv;
        __syncthreads();
#pragma unroll
        for (int kk = 0; kk < 16; ++kk) {
            float4 b4 = *(const float4*)&Bs[kk * 64 + tn0];
            float a0 = As[(tm0 + 0) * 20 + kk];
            float a1 = As[(tm0 + 1) * 20 + kk];
            float a2 = As[(tm0 + 2) * 20 + kk];
            float a3 = As[(tm0 + 3) * 20 + kk];
            acc[0][0] = fmaf(a0, b4.x, acc[0][0]); acc[0][1] = fmaf(a0, b4.y, acc[0][1]);
            acc[0][2] = fmaf(a0, b4.z, acc[0][2]); acc[0][3] = fmaf(a0, b4.w, acc[0][3]);
            acc[1][0] = fmaf(a1, b4.x, acc[1][0]); acc[1][1] = fmaf(a1, b4.y, acc[1][1]);
            acc[1][2] = fmaf(a1, b4.z, acc[1][2]); acc[1][3] = fmaf(a1, b4.w, acc[1][3]);
            acc[2][0] = fmaf(a2, b4.x, acc[2][0]); acc[2][1] = fmaf(a2, b4.y, acc[2][1]);
            acc[2][2] = fmaf(a2, b4.z, acc[2][2]); acc[2][3] = fmaf(a2, b4.w, acc[2][3]);
            acc[3][0] = fmaf(a3, b4.x, acc[3][0]); acc[3][1] = fmaf(a3, b4.y, acc[3][1]);
            acc[3][2] = fmaf(a3, b4.z, acc[3][2]); acc[3][3] = fmaf(a3, b4.w, acc[3][3]);
        }
        __syncthreads();
    }
    float* cp = Cp + (size_t)bs * M * N;
#pragma unroll
    for (int i = 0; i < 4; ++i)
#pragma unroll
        for (int j = 0; j < 4; ++j)
            cp[(size_t)(m0 + tm0 + i) * N + n0 + tn0 + j] = acc[i][j];
}

__global__ void reduce_bias_act(const float* __restrict__ part, const float* __restrict__ bias,
                                float* __restrict__ out, int MN, int N, int S, int relu)
{
    int idx = blockIdx.x * 256 + threadIdx.x;
    if (idx >= MN) return;
    float a = bias[idx % N];
    for (int s = 0; s < S; ++s) a += part[(size_t)s * MN + idx];
    if (relu) a = fmaxf(a, 0.0f);
    out[idx] = a;
}

// ---------------------------------------------------------------------------
// Workspace: 44.3 MB (proven). MFMA sk=8 partials = 8x786432 = Region B.
// ---------------------------------------------------------------------------
extern "C" void kernel_launch(void* const* d_in, const int* in_sizes, int n_in,
                              void* d_out, int out_size, void* d_ws, size_t ws_size,
                              hipStream_t stream)
{
    const float* lab    = (const float*)d_in[0];
    const float* glu    = (const float*)d_in[1];
    const float* timev  = (const float*)d_in[2];
    const float* med    = (const float*)d_in[3];
    const float* ehr    = (const float*)d_in[4];
    const float* ddi    = (const float*)d_in[5];
    const float* tadj   = (const float*)d_in[6];
    const float* Ws1    = (const float*)d_in[7];
    const float* bs1    = (const float*)d_in[8];
    const float* Ws2    = (const float*)d_in[9];
    const float* bs2    = (const float*)d_in[10];
    const float* Wl1    = (const float*)d_in[11];
    const float* bl1    = (const float*)d_in[12];
    const float* Wl2    = (const float*)d_in[13];
    const float* bl2    = (const float*)d_in[14];
    const float* Wl3    = (const float*)d_in[15];
    const float* bl3    = (const float*)d_in[16];
    const float* Wm1    = (const float*)d_in[17];
    const float* bm1    = (const float*)d_in[18];
    const float* Wmq    = (const float*)d_in[19];
    const float* Wmk    = (const float*)d_in[20];
    const float* Wg1    = (const float*)d_in[21];
    const float* bg1    = (const float*)d_in[22];
    const float* Wgq    = (const float*)d_in[23];
    const float* Wgk    = (const float*)d_in[24];
    const float* gWx    = (const float*)d_in[25];
    const float* gWh    = (const float*)d_in[26];
    const float* gb     = (const float*)d_in[27];
    const float* m1Wq   = (const float*)d_in[28];
    const float* m1Wk   = (const float*)d_in[29];
    const float* m1Wv   = (const float*)d_in[30];
    const float* m1Wo   = (const float*)d_in[31];
    const float* m2Wq   = (const float*)d_in[32];
    const float* m2Wk   = (const float*)d_in[33];
    const float* m2Wv   = (const float*)d_in[34];
    const float* m2Wo   = (const float*)d_in[35];
    const float* Wo1    = (const float*)d_in[36];
    const float* bo1    = (const float*)d_in[37];
    const float* Wo2    = (const float*)d_in[38];
    const float* bo2    = (const float*)d_in[39];

    float* W = (float*)d_ws;
    size_t off = 0;
    auto alloc = [&](size_t n) { size_t r = off; off += (n + 3) & ~(size_t)3; return r; };
    // ---- Region A ----
    size_t o_s1      = alloc(512 * 64);
    size_t o_s2      = alloc(512 * 32);
    size_t o_gluenc  = alloc(8192 * 16);
    size_t o_hg      = alloc(8192 * 32);
    size_t o_patient = alloc(8192 * 64);
    size_t o_medh    = alloc(7680 * 64);
    size_t o_medrep  = alloc(7680 * 64);
    size_t o_dm      = alloc(192 * 64);
    size_t o_qh2s    = alloc(192 * 64);
    size_t o_qh1     = alloc(7680 * 64);
    size_t o_kh1     = alloc(8192 * 64);
    size_t o_vh1     = alloc(8192 * 64);
    size_t o_Een     = alloc(7680 * 64);
    size_t o_kh2 = o_medh;      // aliases dead-after-mha1 buffers
    size_t o_vh2 = o_qh1;
    size_t o_abf = 0;           // Abf aliases Region A start after mha2
    // ---- Regions B, C ----
    size_t o_so      = alloc((size_t)512 * 12288);   // attention output (pre-Wo)
    size_t o_h1      = alloc((size_t)512 * 1536);
    size_t o_part    = o_so;    // split-K partials alias region B

    // static path
    {
        dim3 g(1, 8, 4);
        gemm_sk<0><<<g, 256, 0, stream>>>(lab, Ws1, W + o_part, 512, 64, 256, 64);
        reduce_bias_act<<<128, 256, 0, stream>>>(W + o_part, bs1, W + o_s1, 512 * 64, 64, 4, 1);
    }
    gemm_small<<<64, 256, 0, stream>>>(W + o_s1, Ws2, bs2, W + o_s2, 512, 32, 64, 1, 0);
    // GRU (wave-parallel)
    gru_wave<<<512, 256, 0, stream>>>(glu, timev, gWx, gWh, gb, W + o_gluenc);
    // glu attn encoder -> patient_rep
    gemm_small<<<1024, 256, 0, stream>>>(W + o_gluenc, Wg1, bg1, W + o_hg, 8192, 32, 16, 2, 0);
    glu_attn<<<512, 256, 0, stream>>>(W + o_hg, Wgq, Wgk, W + o_s2, W + o_patient);
    // med attn encoder
    gemm_small<<<1920, 256, 0, stream>>>(med, Wm1, bm1, W + o_medh, 7680, 64, 192, 2, 15);
    med_attn<<<512, 256, 0, stream>>>(W + o_medh, Wmq, Wmk, W + o_medrep);
    // drug memory + shared qh2
    drugmem_kernel<<<48, 256, 0, stream>>>(ehr, tadj, ddi, Wl1, bl1, Wl2, bl2, Wl3, bl3, W + o_dm);
    gemm_small<<<48, 256, 0, stream>>>(W + o_dm, m2Wq, nullptr, W + o_qh2s, 192, 64, 64, 0, 0);
    // MHA-1 (K/V fused)
    gemm_small<<<1920, 256, 0, stream>>>(W + o_medrep, m1Wq, nullptr, W + o_qh1, 7680, 64, 64, 0, 0);
    gemm_small_dual<<<2048, 256, 0, stream>>>(W + o_patient, m1Wk, m1Wv,
                                              W + o_kh1, W + o_vh1, 8192, 64, 64);
    mha1_attn<<<512, 256, 0, stream>>>(W + o_qh1, W + o_kh1, W + o_vh1, m1Wo, W + o_Een);
    // MHA-2 (K/V fused; no Wo epilogue)
    gemm_small_dual<<<1920, 256, 0, stream>>>(W + o_Een, m2Wk, m2Wv,
                                              W + o_kh2, W + o_vh2, 7680, 64, 64);
    mha2_attn2<<<2048, 256, 0, stream>>>(W + o_qh2s, W + o_kh2, W + o_vh2, W + o_so);
    // Abf = bf16(relu(so @ m2_Wo))
    gemm64_relu_bf16<<<1536, 256, 0, stream>>>(W + o_so, m2Wo, (unsigned short*)(W + o_abf));
    // h1 = relu(Abf @ bf16(Wo1) + bo1), MFMA 128x64 tile, split-K=8, prefetch
    {
        dim3 g(24, 4, 8);
        gemm_mfma_bf16<<<g, 256, 0, stream>>>((const unsigned short*)(W + o_abf), Wo1,
                                              W + o_part, 512, 1536, 12288, 1536);
        reduce_bias_act<<<3072, 256, 0, stream>>>(W + o_part, bo1, W + o_h1, 512 * 1536, 1536, 8, 1);
    }
    // out = h1 @ Wo2 + bo2 (f32 split-K=16)
    {
        dim3 g(3, 8, 16);
        gemm_sk<0><<<g, 256, 0, stream>>>(W + o_h1, Wo2, W + o_part, 512, 192, 1536, 96);
        reduce_bias_act<<<384, 256, 0, stream>>>(W + o_part, bo2, (float*)d_out, 512 * 192, 192, 16, 0);
    }
}

// Round 19
// 254.847 us; speedup vs baseline: 1.2032x; 1.2032x over previous
//
#include <hip/hip_runtime.h>
#include <math.h>

#define DEVINL __device__ __forceinline__

DEVINL float sigm(float x) { return 1.0f / (1.0f + __expf(-x)); }
DEVINL float tanh_fast(float x) { return 2.0f / (1.0f + __expf(-2.0f * x)) - 1.0f; }
DEVINL unsigned short bf16rne(float f) {
    unsigned u = __float_as_uint(f);
    return (unsigned short)((u + 0x7FFFu + ((u >> 16) & 1u)) >> 16);
}

typedef __attribute__((ext_vector_type(8))) short bf16x8;
typedef __attribute__((ext_vector_type(4))) float f32x4;

// ---------------------------------------------------------------------------
// Generic small GEMM, K-unrolled x4 (R11-verified)
// ---------------------------------------------------------------------------
__global__ void gemm_small(const float* __restrict__ A, const float* __restrict__ W,
                           const float* __restrict__ bias, float* __restrict__ C,
                           int M, int N, int K, int act, int vgroup)
{
    int idx = blockIdx.x * blockDim.x + threadIdx.x;
    if (idx >= M * N) return;
    int m = idx / N, n = idx - m * N;
    int am = m;
    if (vgroup) { int g = m / vgroup; am = g * (vgroup + 1) + (m - g * vgroup); }
    const float* a = A + (size_t)am * K;
    const float* w = W + n;
    float acc = bias ? bias[n] : 0.0f;
    for (int k = 0; k < K; k += 4) {
        float4 av = *(const float4*)&a[k];
        float w0 = w[(size_t)k * N];
        float w1 = w[(size_t)(k + 1) * N];
        float w2 = w[(size_t)(k + 2) * N];
        float w3 = w[(size_t)(k + 3) * N];
        acc = fmaf(av.x, w0, acc);
        acc = fmaf(av.y, w1, acc);
        acc = fmaf(av.z, w2, acc);
        acc = fmaf(av.w, w3, acc);
    }
    if (act == 1) acc = fmaxf(acc, 0.0f);
    else if (act == 2) acc = tanh_fast(acc);
    C[idx] = acc;
}

// ---------------------------------------------------------------------------
// Dual-output small GEMM (R12-verified): C1 = A@W1, C2 = A@W2, A read once.
// ---------------------------------------------------------------------------
__global__ void gemm_small_dual(const float* __restrict__ A,
    const float* __restrict__ W1, const float* __restrict__ W2,
    float* __restrict__ C1, float* __restrict__ C2, int M, int N, int K)
{
    int idx = blockIdx.x * blockDim.x + threadIdx.x;
    if (idx >= M * N) return;
    int m = idx / N, n = idx - m * N;
    const float* a = A + (size_t)m * K;
    const float* w1 = W1 + n;
    const float* w2 = W2 + n;
    float acc1 = 0.0f, acc2 = 0.0f;
    for (int k = 0; k < K; k += 4) {
        float4 av = *(const float4*)&a[k];
        float p0 = w1[(size_t)k * N],       q0 = w2[(size_t)k * N];
        float p1 = w1[(size_t)(k + 1) * N], q1 = w2[(size_t)(k + 1) * N];
        float p2 = w1[(size_t)(k + 2) * N], q2 = w2[(size_t)(k + 2) * N];
        float p3 = w1[(size_t)(k + 3) * N], q3 = w2[(size_t)(k + 3) * N];
        acc1 = fmaf(av.x, p0, acc1); acc2 = fmaf(av.x, q0, acc2);
        acc1 = fmaf(av.y, p1, acc1); acc2 = fmaf(av.y, q1, acc2);
        acc1 = fmaf(av.z, p2, acc1); acc2 = fmaf(av.z, q2, acc2);
        acc1 = fmaf(av.w, p3, acc1); acc2 = fmaf(av.w, q3, acc2);
    }
    C1[idx] = acc1;
    C2[idx] = acc2;
}

// ---------------------------------------------------------------------------
// Wave-parallel GRU (R6-verified)
// ---------------------------------------------------------------------------
__global__ __launch_bounds__(256) void gru_wave(const float* __restrict__ glu,
    const float* __restrict__ timev, const float* __restrict__ Wx,
    const float* __restrict__ Wh, const float* __restrict__ bb,
    float* __restrict__ out)
{
    __shared__ float sWh[768], sWx[96], sb[48];
    int tid = threadIdx.x;
    for (int i = tid; i < 768; i += 256) sWh[i] = Wh[i];
    if (tid < 96) sWx[tid] = Wx[tid];
    if (tid < 48) sb[tid] = bb[tid];
    __syncthreads();
    int j = tid & 15;
    int seq = blockIdx.x * 16 + (tid >> 4);
    int gbase = (tid & 63) & 0x30;
    float whz[16], whr[16], whn[16];
#pragma unroll
    for (int i = 0; i < 16; ++i) {
        whz[i] = sWh[i * 48 + j];
        whr[i] = sWh[i * 48 + 16 + j];
        whn[i] = sWh[i * 48 + 32 + j];
    }
    float wxz0 = sWx[j],      wxr0 = sWx[16 + j], wxn0 = sWx[32 + j];
    float wxz1 = sWx[48 + j], wxr1 = sWx[64 + j], wxn1 = sWx[80 + j];
    float bz = sb[j], br = sb[16 + j], bn = sb[32 + j];
    const float* gp = glu + (size_t)seq * 48;
    const float* tp = timev + (size_t)seq * 48;
    float h = 0.0f;
    for (int t = 0; t < 48; ++t) {
        float gl = gp[t], tm = tp[t];
        float gz = fmaf(gl, wxz0, fmaf(tm, wxz1, bz));
        float gr = fmaf(gl, wxr0, fmaf(tm, wxr1, br));
        float gn = fmaf(gl, wxn0, fmaf(tm, wxn1, bn));
        float ghn = 0.0f;
#pragma unroll
        for (int i = 0; i < 16; ++i) {
            float hb = __shfl(h, gbase + i, 64);
            gz = fmaf(hb, whz[i], gz);
            gr = fmaf(hb, whr[i], gr);
            ghn = fmaf(hb, whn[i], ghn);
        }
        float z = sigm(gz), r = sigm(gr);
        float n = tanh_fast(gn + r * ghn);
        h = (1.0f - z) * n + z * h;
    }
    out[(size_t)seq * 16 + j] = h;
}

// ---------------------------------------------------------------------------
// glu attn_enc (per batch) -> patient_rep with static concat
// ---------------------------------------------------------------------------
__global__ __launch_bounds__(256) void glu_attn(const float* __restrict__ hg,
    const float* __restrict__ Wq, const float* __restrict__ Wk,
    const float* __restrict__ s2, float* __restrict__ patient)
{
    int b = blockIdx.x, tid = threadIdx.x;
    __shared__ float sh[512], sq[256], sk[256], ss[256];
    sh[tid] = hg[(size_t)b * 512 + tid];
    sh[256 + tid] = hg[(size_t)b * 512 + 256 + tid];
    __syncthreads();
    {
        int p = tid >> 4, j = tid & 15;
        float aq = 0.0f, ak = 0.0f;
        for (int i = 0; i < 32; ++i) {
            float hv = sh[p * 32 + i];
            aq = fmaf(hv, Wq[i * 16 + j], aq);
            ak = fmaf(hv, Wk[i * 16 + j], ak);
        }
        sq[tid] = aq; sk[tid] = ak;
    }
    __syncthreads();
    {
        int p = tid >> 4, pk = tid & 15;
        float a = 0.0f;
        for (int j = 0; j < 16; ++j) a = fmaf(sq[p * 16 + j], sk[pk * 16 + j], a);
        ss[tid] = a * 0.25f;
    }
    __syncthreads();
    if (tid < 16) {
        float mx = -1e30f;
        for (int k = 0; k < 16; ++k) mx = fmaxf(mx, ss[tid * 16 + k]);
        float sum = 0.0f;
        for (int k = 0; k < 16; ++k) { float e = __expf(ss[tid * 16 + k] - mx); ss[tid * 16 + k] = e; sum += e; }
        float inv = 1.0f / sum;
        for (int k = 0; k < 16; ++k) ss[tid * 16 + k] *= inv;
    }
    __syncthreads();
    for (int o = tid; o < 512; o += 256) {
        int p = o >> 5, c = o & 31;
        float acc = 0.0f;
        for (int pk = 0; pk < 16; ++pk) acc = fmaf(ss[p * 16 + pk], sh[pk * 32 + c], acc);
        patient[((size_t)b * 16 + p) * 64 + c] = acc;
        patient[((size_t)b * 16 + p) * 64 + 32 + c] = s2[(size_t)b * 32 + c];
    }
}

// ---------------------------------------------------------------------------
// med attn_enc (per batch)
// ---------------------------------------------------------------------------
__global__ __launch_bounds__(256) void med_attn(const float* __restrict__ hm,
    const float* __restrict__ Wq, const float* __restrict__ Wk,
    float* __restrict__ med_rep)
{
    int b = blockIdx.x, tid = threadIdx.x;
    __shared__ float sh[960], sq[480], sk[480], ss[225];
    for (int i = tid; i < 960; i += 256) sh[i] = hm[(size_t)b * 960 + i];
    __syncthreads();
    for (int o = tid; o < 480; o += 256) {
        int p = o >> 5, j = o & 31;
        float aq = 0.0f, ak = 0.0f;
        for (int i = 0; i < 64; ++i) {
            float hv = sh[p * 64 + i];
            aq = fmaf(hv, Wq[i * 32 + j], aq);
            ak = fmaf(hv, Wk[i * 32 + j], ak);
        }
        sq[o] = aq; sk[o] = ak;
    }
    __syncthreads();
    if (tid < 225) {
        int p = tid / 15, pk = tid - p * 15;
        float a = 0.0f;
        for (int j = 0; j < 32; ++j) a = fmaf(sq[p * 32 + j], sk[pk * 32 + j], a);
        ss[tid] = a * 0.17677669529663687f;
    }
    __syncthreads();
    if (tid < 15) {
        float mx = -1e30f;
        for (int k = 0; k < 15; ++k) mx = fmaxf(mx, ss[tid * 15 + k]);
        float sum = 0.0f;
        for (int k = 0; k < 15; ++k) { float e = __expf(ss[tid * 15 + k] - mx); ss[tid * 15 + k] = e; sum += e; }
        float inv = 1.0f / sum;
        for (int k = 0; k < 15; ++k) ss[tid * 15 + k] *= inv;
    }
    __syncthreads();
    for (int o = tid; o < 960; o += 256) {
        int p = o >> 6, c = o & 63;
        float acc = 0.0f;
        for (int pk = 0; pk < 15; ++pk) acc = fmaf(ss[p * 15 + pk], sh[pk * 64 + c], acc);
        med_rep[(size_t)b * 960 + o] = acc;
    }
}

// ---------------------------------------------------------------------------
// drug_mem[192,64]
// ---------------------------------------------------------------------------
__global__ void drugmem_kernel(const float* __restrict__ ehr, const float* __restrict__ tadj,
    const float* __restrict__ ddi,
    const float* __restrict__ Wl1, const float* __restrict__ bl1,
    const float* __restrict__ Wl2, const float* __restrict__ bl2,
    const float* __restrict__ Wl3, const float* __restrict__ bl3,
    float* __restrict__ dm)
{
    int idx = blockIdx.x * 256 + threadIdx.x;
    if (idx >= 192 * 64) return;
    int m = idx >> 6, n = idx & 63;
    float acc = bl1[n] + bl2[n] - bl3[n];
    for (int k = 0; k < 192; ++k) {
        acc = fmaf(ehr[m * 192 + k], Wl1[k * 64 + n], acc);
        acc = fmaf(tadj[m * 192 + k], Wl2[k * 64 + n], acc);
        acc = fmaf(-ddi[m * 192 + k], Wl3[k * 64 + n], acc);
    }
    dm[idx] = acc;
}

// ---------------------------------------------------------------------------
// MHA-1 (per batch). sq/sk padded to stride 68.
// ---------------------------------------------------------------------------
__global__ __launch_bounds__(256) void mha1_attn(const float* __restrict__ qh1,
    const float* __restrict__ kh1, const float* __restrict__ vh1,
    const float* __restrict__ Wo, float* __restrict__ Een)
{
    int b = blockIdx.x, tid = threadIdx.x;
    __shared__ float sq[1020], sk[1088], sv[1024], ss[960], so[960];
    for (int i = tid; i < 960; i += 256) sq[(i >> 6) * 68 + (i & 63)] = qh1[(size_t)b * 960 + i];
    for (int i = tid; i < 1024; i += 256) {
        sk[(i >> 6) * 68 + (i & 63)] = kh1[(size_t)b * 1024 + i];
        sv[i] = vh1[(size_t)b * 1024 + i];
    }
    __syncthreads();
    for (int o = tid; o < 960; o += 256) {
        int hh = o / 240, rem = o - hh * 240, q = rem >> 4, k = rem & 15;
        float a = 0.0f;
        for (int d = 0; d < 16; ++d) a = fmaf(sq[q * 68 + hh * 16 + d], sk[k * 68 + hh * 16 + d], a);
        ss[o] = a * 0.25f;
    }
    __syncthreads();
    if (tid < 60) {
        int base = tid * 16;
        float mx = -1e30f;
        for (int k = 0; k < 16; ++k) mx = fmaxf(mx, ss[base + k]);
        float sum = 0.0f;
        for (int k = 0; k < 16; ++k) { float e = __expf(ss[base + k] - mx); ss[base + k] = e; sum += e; }
        float inv = 1.0f / sum;
        for (int k = 0; k < 16; ++k) ss[base + k] *= inv;
    }
    __syncthreads();
    for (int o = tid; o < 960; o += 256) {
        int q = o >> 6, j = o & 63, hh = j >> 4;
        float a = 0.0f;
        for (int k = 0; k < 16; ++k) a = fmaf(ss[hh * 240 + q * 16 + k], sv[k * 64 + j], a);
        so[o] = a;
    }
    __syncthreads();
    for (int o = tid; o < 960; o += 256) {
        int q = o >> 6, c = o & 63;
        float a = 0.0f;
        for (int j = 0; j < 64; ++j) a = fmaf(so[q * 64 + j], Wo[j * 64 + c], a);
        Een[(size_t)b * 960 + o] = a;
    }
}

// ---------------------------------------------------------------------------
// MHA-2 v2 (R8-verified): block per (batch, q-chunk); stride-68 K; no Wo.
// ---------------------------------------------------------------------------
__global__ __launch_bounds__(256) void mha2_attn2(const float* __restrict__ qh2,
    const float* __restrict__ kh2, const float* __restrict__ vh2,
    float* __restrict__ so_all)
{
    int b = blockIdx.x >> 2, q0 = (blockIdx.x & 3) * 48;
    int tid = threadIdx.x;
    __shared__ float skp[1020], sv[960], ss[2880];
    for (int i = tid; i < 960; i += 256) {
        skp[(i >> 6) * 68 + (i & 63)] = kh2[(size_t)b * 960 + i];
        sv[i] = vh2[(size_t)b * 960 + i];
    }
    __syncthreads();
    for (int o = tid; o < 2880; o += 256) {
        int hh = o / 720, rem = o - hh * 720, q = rem / 15, k = rem - q * 15;
        const float* qp = qh2 + (size_t)(q0 + q) * 64 + hh * 16;
        float a = 0.0f;
        for (int d = 0; d < 16; ++d) a = fmaf(qp[d], skp[k * 68 + hh * 16 + d], a);
        ss[o] = a * 0.25f;
    }
    __syncthreads();
    if (tid < 192) {
        int hh = tid / 48, q = tid - hh * 48;
        int base = hh * 720 + q * 15;
        float mx = -1e30f;
        for (int k = 0; k < 15; ++k) mx = fmaxf(mx, ss[base + k]);
        float sum = 0.0f;
        for (int k = 0; k < 15; ++k) { float e = __expf(ss[base + k] - mx); ss[base + k] = e; sum += e; }
        float inv = 1.0f / sum;
        for (int k = 0; k < 15; ++k) ss[base + k] *= inv;
    }
    __syncthreads();
    for (int o = tid; o < 3072; o += 256) {
        int q = o >> 6, j = o & 63, hh = j >> 4;
        float a = 0.0f;
        for (int k = 0; k < 15; ++k) a = fmaf(ss[hh * 720 + q * 15 + k], sv[k * 64 + j], a);
        so_all[((size_t)b * 192 + q0 + q) * 64 + j] = a;
    }
}

// ---------------------------------------------------------------------------
// Abf = bf16(relu(so[98304,64] @ Wo[64,64])), f32 math, fused epilogue.
// ---------------------------------------------------------------------------
__global__ __launch_bounds__(256) void gemm64_relu_bf16(const float* __restrict__ A,
    const float* __restrict__ B, unsigned short* __restrict__ Obf)
{
    __shared__ float As[64 * 20];
    __shared__ float Bs[16 * 64];
    int tid = threadIdx.x;
    int m0 = blockIdx.x * 64;
    float acc[4][4] = {};
    int arow = tid >> 2, akq = (tid & 3) << 2;
    int brow = tid >> 4, bnq = (tid & 15) << 2;
    int tm0 = (tid >> 4) << 2, tn0 = (tid & 15) << 2;
    for (int kt = 0; kt < 64; kt += 16) {
        float4 av = *(const float4*)&A[(size_t)(m0 + arow) * 64 + kt + akq];
        *(float4*)&As[arow * 20 + akq] = av;
        float4 bv = *(const float4*)&B[(size_t)(kt + brow) * 64 + bnq];
        *(float4*)&Bs[brow * 64 + bnq] = bv;
        __syncthreads();
#pragma unroll
        for (int kk = 0; kk < 16; ++kk) {
            float4 b4 = *(const float4*)&Bs[kk * 64 + tn0];
            float a0 = As[(tm0 + 0) * 20 + kk];
            float a1 = As[(tm0 + 1) * 20 + kk];
            float a2 = As[(tm0 + 2) * 20 + kk];
            float a3 = As[(tm0 + 3) * 20 + kk];
            acc[0][0] = fmaf(a0, b4.x, acc[0][0]); acc[0][1] = fmaf(a0, b4.y, acc[0][1]);
            acc[0][2] = fmaf(a0, b4.z, acc[0][2]); acc[0][3] = fmaf(a0, b4.w, acc[0][3]);
            acc[1][0] = fmaf(a1, b4.x, acc[1][0]); acc[1][1] = fmaf(a1, b4.y, acc[1][1]);
            acc[1][2] = fmaf(a1, b4.z, acc[1][2]); acc[1][3] = fmaf(a1, b4.w, acc[1][3]);
            acc[2][0] = fmaf(a2, b4.x, acc[2][0]); acc[2][1] = fmaf(a2, b4.y, acc[2][1]);
            acc[2][2] = fmaf(a2, b4.z, acc[2][2]); acc[2][3] = fmaf(a2, b4.w, acc[2][3]);
            acc[3][0] = fmaf(a3, b4.x, acc[3][0]); acc[3][1] = fmaf(a3, b4.y, acc[3][1]);
            acc[3][2] = fmaf(a3, b4.z, acc[3][2]); acc[3][3] = fmaf(a3, b4.w, acc[3][3]);
        }
        __syncthreads();
    }
#pragma unroll
    for (int i = 0; i < 4; ++i) {
        unsigned r0 = (unsigned)bf16rne(fmaxf(acc[i][0], 0.f)) | ((unsigned)bf16rne(fmaxf(acc[i][1], 0.f)) << 16);
        unsigned r1 = (unsigned)bf16rne(fmaxf(acc[i][2], 0.f)) | ((unsigned)bf16rne(fmaxf(acc[i][3], 0.f)) << 16);
        uint2 v = { r0, r1 };
        *(uint2*)&Obf[(size_t)(m0 + tm0 + i) * 64 + tn0] = v;
    }
}

// ---------------------------------------------------------------------------
// MFMA bf16 split-K GEMM — EXACT R12 kernel (passed at 255us total, 71us
// dispatch). 128m x 64n tile, BK=64, sk=8, conflict-free scalar B staging.
// Resubmitted byte-identical: R18's abort on THIS source (which passed R12)
// proves aborts are environmental, not source-determined.
// ---------------------------------------------------------------------------
__global__ __launch_bounds__(256) void gemm_mfma_bf16(
    const unsigned short* __restrict__ Abf, const float* __restrict__ B,
    float* __restrict__ Cp, int M, int N, int K, int klen)
{
    __shared__ unsigned short As[128 * 64];   // 16 KB, XOR-swizzled rows
    __shared__ unsigned short Bs[64 * 64];    // 8 KB, [n][k] XOR-swizzled
    int tid = threadIdx.x;
    int lane = tid & 63, w = tid >> 6;        // 4 waves, wave w owns m-rows [w*32, w*32+32)
    int n0 = blockIdx.x * 64, m0 = blockIdx.y * 128;
    int kbase0 = blockIdx.z * klen;
    f32x4 acc[2][4] = {};

    int bn = tid & 63, bkc = (tid >> 6) * 16;
    for (int kt = 0; kt < klen; kt += 64) {
        int kb = kbase0 + kt;
        // stage A: 128 rows x 64 k = 1024 chunks of 16B; 4 per thread
#pragma unroll
        for (int c = 0; c < 4; ++c) {
            int ch = tid + c * 256;
            int row = ch >> 3, kc0 = (ch & 7) << 3;
            uint4 v = *(const uint4*)&Abf[(size_t)(m0 + row) * K + kb + kc0];
            int bo = ((row << 7) + (kc0 << 1)) ^ ((row & 7) << 4);
            *(uint4*)((char*)As + bo) = v;
        }
        // stage B transposed ([n][k]) with f32->bf16 convert
        {
            const float* bp = &B[(size_t)(kb + bkc) * N + n0 + bn];
#pragma unroll
            for (int j = 0; j < 16; j += 2) {
                float f0 = bp[(size_t)j * N];
                float f1 = bp[(size_t)(j + 1) * N];
                unsigned u = (unsigned)bf16rne(f0) | ((unsigned)bf16rne(f1) << 16);
                int k = bkc + j;
                int bo = ((bn << 7) + (k << 1)) ^ ((bn & 7) << 4);
                *(unsigned*)((char*)Bs + bo) = u;
            }
        }
        __syncthreads();
#pragma unroll
        for (int kk = 0; kk < 64; kk += 32) {
            int kb2 = (kk + ((lane >> 4) << 3)) << 1;
            bf16x8 af[2], bfg[4];
#pragma unroll
            for (int fm = 0; fm < 2; ++fm) {
                int row = (w << 5) + (fm << 4) + (lane & 15);
                af[fm] = *(const bf16x8*)((const char*)As + (((row << 7) + kb2) ^ ((row & 7) << 4)));
            }
#pragma unroll
            for (int fn = 0; fn < 4; ++fn) {
                int col = (fn << 4) + (lane & 15);
                bfg[fn] = *(const bf16x8*)((const char*)Bs + (((col << 7) + kb2) ^ ((col & 7) << 4)));
            }
#pragma unroll
            for (int fm = 0; fm < 2; ++fm)
#pragma unroll
                for (int fn = 0; fn < 4; ++fn)
                    acc[fm][fn] = __builtin_amdgcn_mfma_f32_16x16x32_bf16(af[fm], bfg[fn], acc[fm][fn], 0, 0, 0);
        }
        __syncthreads();
    }
    float* cp = Cp + (size_t)blockIdx.z * M * N;
#pragma unroll
    for (int fm = 0; fm < 2; ++fm)
#pragma unroll
        for (int fn = 0; fn < 4; ++fn) {
            int row = m0 + (w << 5) + (fm << 4) + ((lane >> 4) << 2);
            int col = n0 + (fn << 4) + (lane & 15);
#pragma unroll
            for (int r = 0; r < 4; ++r)
                cp[(size_t)(row + r) * N + col] = acc[fm][fn][r];
        }
}

// ---------------------------------------------------------------------------
// Split-K tiled f32 GEMM
// ---------------------------------------------------------------------------
template <int RELU_A>
__global__ __launch_bounds__(256) void gemm_sk(const float* __restrict__ A,
    const float* __restrict__ B, float* __restrict__ Cp,
    int M, int N, int K, int klen)
{
    __shared__ float As[64 * 20];
    __shared__ float Bs[16 * 64];
    int tid = threadIdx.x;
    int n0 = blockIdx.x * 64, m0 = blockIdx.y * 64;
    int bs = blockIdx.z;
    int kbase0 = bs * klen;
    float acc[4][4] = {};
    int arow = tid >> 2, akq = (tid & 3) << 2;
    int brow = tid >> 4, bnq = (tid & 15) << 2;
    int tm0 = (tid >> 4) << 2, tn0 = (tid & 15) << 2;
    for (int kt = 0; kt < klen; kt += 16) {
        int kb = kbase0 + kt;
        float4 av = *(const float4*)&A[(size_t)(m0 + arow) * K + kb + akq];
        if (RELU_A) {
            av.x = fmaxf(av.x, 0.0f); av.y = fmaxf(av.y, 0.0f);
            av.z = fmaxf(av.z, 0.0f); av.w = fmaxf(av.w, 0.0f);
        }
        *(float4*)&As[arow * 20 + akq] = av;
        float4 bv = *(const float4*)&B[(size_t)(kb + brow) * N + n0 + bnq];
        *(float4*)&Bs[brow * 64 + bnq] = bv;
        __syncthreads();
#pragma unroll
        for (int kk = 0; kk < 16; ++kk) {
            float4 b4 = *(const float4*)&Bs[kk * 64 + tn0];
            float a0 = As[(tm0 + 0) * 20 + kk];
            float a1 = As[(tm0 + 1) * 20 + kk];
            float a2 = As[(tm0 + 2) * 20 + kk];
            float a3 = As[(tm0 + 3) * 20 + kk];
            acc[0][0] = fmaf(a0, b4.x, acc[0][0]); acc[0][1] = fmaf(a0, b4.y, acc[0][1]);
            acc[0][2] = fmaf(a0, b4.z, acc[0][2]); acc[0][3] = fmaf(a0, b4.w, acc[0][3]);
            acc[1][0] = fmaf(a1, b4.x, acc[1][0]); acc[1][1] = fmaf(a1, b4.y, acc[1][1]);
            acc[1][2] = fmaf(a1, b4.z, acc[1][2]); acc[1][3] = fmaf(a1, b4.w, acc[1][3]);
            acc[2][0] = fmaf(a2, b4.x, acc[2][0]); acc[2][1] = fmaf(a2, b4.y, acc[2][1]);
            acc[2][2] = fmaf(a2, b4.z, acc[2][2]); acc[2][3] = fmaf(a2, b4.w, acc[2][3]);
            acc[3][0] = fmaf(a3, b4.x, acc[3][0]); acc[3][1] = fmaf(a3, b4.y, acc[3][1]);
            acc[3][2] = fmaf(a3, b4.z, acc[3][2]); acc[3][3] = fmaf(a3, b4.w, acc[3][3]);
        }
        __syncthreads();
    }
    float* cp = Cp + (size_t)bs * M * N;
#pragma unroll
    for (int i = 0; i < 4; ++i)
#pragma unroll
        for (int j = 0; j < 4; ++j)
            cp[(size_t)(m0 + tm0 + i) * N + n0 + tn0 + j] = acc[i][j];
}

__global__ void reduce_bias_act(const float* __restrict__ part, const float* __restrict__ bias,
                                float* __restrict__ out, int MN, int N, int S, int relu)
{
    int idx = blockIdx.x * 256 + threadIdx.x;
    if (idx >= MN) return;
    float a = bias[idx % N];
    for (int s = 0; s < S; ++s) a += part[(size_t)s * MN + idx];
    if (relu) a = fmaxf(a, 0.0f);
    out[idx] = a;
}

// ---------------------------------------------------------------------------
// Workspace: 44.3 MB (proven). MFMA sk=8 partials = 8x786432 = Region B.
// ---------------------------------------------------------------------------
extern "C" void kernel_launch(void* const* d_in, const int* in_sizes, int n_in,
                              void* d_out, int out_size, void* d_ws, size_t ws_size,
                              hipStream_t stream)
{
    const float* lab    = (const float*)d_in[0];
    const float* glu    = (const float*)d_in[1];
    const float* timev  = (const float*)d_in[2];
    const float* med    = (const float*)d_in[3];
    const float* ehr    = (const float*)d_in[4];
    const float* ddi    = (const float*)d_in[5];
    const float* tadj   = (const float*)d_in[6];
    const float* Ws1    = (const float*)d_in[7];
    const float* bs1    = (const float*)d_in[8];
    const float* Ws2    = (const float*)d_in[9];
    const float* bs2    = (const float*)d_in[10];
    const float* Wl1    = (const float*)d_in[11];
    const float* bl1    = (const float*)d_in[12];
    const float* Wl2    = (const float*)d_in[13];
    const float* bl2    = (const float*)d_in[14];
    const float* Wl3    = (const float*)d_in[15];
    const float* bl3    = (const float*)d_in[16];
    const float* Wm1    = (const float*)d_in[17];
    const float* bm1    = (const float*)d_in[18];
    const float* Wmq    = (const float*)d_in[19];
    const float* Wmk    = (const float*)d_in[20];
    const float* Wg1    = (const float*)d_in[21];
    const float* bg1    = (const float*)d_in[22];
    const float* Wgq    = (const float*)d_in[23];
    const float* Wgk    = (const float*)d_in[24];
    const float* gWx    = (const float*)d_in[25];
    const float* gWh    = (const float*)d_in[26];
    const float* gb     = (const float*)d_in[27];
    const float* m1Wq   = (const float*)d_in[28];
    const float* m1Wk   = (const float*)d_in[29];
    const float* m1Wv   = (const float*)d_in[30];
    const float* m1Wo   = (const float*)d_in[31];
    const float* m2Wq   = (const float*)d_in[32];
    const float* m2Wk   = (const float*)d_in[33];
    const float* m2Wv   = (const float*)d_in[34];
    const float* m2Wo   = (const float*)d_in[35];
    const float* Wo1    = (const float*)d_in[36];
    const float* bo1    = (const float*)d_in[37];
    const float* Wo2    = (const float*)d_in[38];
    const float* bo2    = (const float*)d_in[39];

    float* W = (float*)d_ws;
    size_t off = 0;
    auto alloc = [&](size_t n) { size_t r = off; off += (n + 3) & ~(size_t)3; return r; };
    // ---- Region A ----
    size_t o_s1      = alloc(512 * 64);
    size_t o_s2      = alloc(512 * 32);
    size_t o_gluenc  = alloc(8192 * 16);
    size_t o_hg      = alloc(8192 * 32);
    size_t o_patient = alloc(8192 * 64);
    size_t o_medh    = alloc(7680 * 64);
    size_t o_medrep  = alloc(7680 * 64);
    size_t o_dm      = alloc(192 * 64);
    size_t o_qh2s    = alloc(192 * 64);
    size_t o_qh1     = alloc(7680 * 64);
    size_t o_kh1     = alloc(8192 * 64);
    size_t o_vh1     = alloc(8192 * 64);
    size_t o_Een     = alloc(7680 * 64);
    size_t o_kh2 = o_medh;      // aliases dead-after-mha1 buffers
    size_t o_vh2 = o_qh1;
    size_t o_abf = 0;           // Abf aliases Region A start after mha2
    // ---- Regions B, C ----
    size_t o_so      = alloc((size_t)512 * 12288);   // attention output (pre-Wo)
    size_t o_h1      = alloc((size_t)512 * 1536);
    size_t o_part    = o_so;    // split-K partials alias region B

    // static path
    {
        dim3 g(1, 8, 4);
        gemm_sk<0><<<g, 256, 0, stream>>>(lab, Ws1, W + o_part, 512, 64, 256, 64);
        reduce_bias_act<<<128, 256, 0, stream>>>(W + o_part, bs1, W + o_s1, 512 * 64, 64, 4, 1);
    }
    gemm_small<<<64, 256, 0, stream>>>(W + o_s1, Ws2, bs2, W + o_s2, 512, 32, 64, 1, 0);
    // GRU (wave-parallel)
    gru_wave<<<512, 256, 0, stream>>>(glu, timev, gWx, gWh, gb, W + o_gluenc);
    // glu attn encoder -> patient_rep
    gemm_small<<<1024, 256, 0, stream>>>(W + o_gluenc, Wg1, bg1, W + o_hg, 8192, 32, 16, 2, 0);
    glu_attn<<<512, 256, 0, stream>>>(W + o_hg, Wgq, Wgk, W + o_s2, W + o_patient);
    // med attn encoder
    gemm_small<<<1920, 256, 0, stream>>>(med, Wm1, bm1, W + o_medh, 7680, 64, 192, 2, 15);
    med_attn<<<512, 256, 0, stream>>>(W + o_medh, Wmq, Wmk, W + o_medrep);
    // drug memory + shared qh2
    drugmem_kernel<<<48, 256, 0, stream>>>(ehr, tadj, ddi, Wl1, bl1, Wl2, bl2, Wl3, bl3, W + o_dm);
    gemm_small<<<48, 256, 0, stream>>>(W + o_dm, m2Wq, nullptr, W + o_qh2s, 192, 64, 64, 0, 0);
    // MHA-1 (K/V fused)
    gemm_small<<<1920, 256, 0, stream>>>(W + o_medrep, m1Wq, nullptr, W + o_qh1, 7680, 64, 64, 0, 0);
    gemm_small_dual<<<2048, 256, 0, stream>>>(W + o_patient, m1Wk, m1Wv,
                                              W + o_kh1, W + o_vh1, 8192, 64, 64);
    mha1_attn<<<512, 256, 0, stream>>>(W + o_qh1, W + o_kh1, W + o_vh1, m1Wo, W + o_Een);
    // MHA-2 (K/V fused; no Wo epilogue)
    gemm_small_dual<<<1920, 256, 0, stream>>>(W + o_Een, m2Wk, m2Wv,
                                              W + o_kh2, W + o_vh2, 7680, 64, 64);
    mha2_attn2<<<2048, 256, 0, stream>>>(W + o_qh2s, W + o_kh2, W + o_vh2, W + o_so);
    // Abf = bf16(relu(so @ m2_Wo))
    gemm64_relu_bf16<<<1536, 256, 0, stream>>>(W + o_so, m2Wo, (unsigned short*)(W + o_abf));
    // h1 = relu(Abf @ bf16(Wo1) + bo1), MFMA 128x64 tile, split-K=8
    {
        dim3 g(24, 4, 8);
        gemm_mfma_bf16<<<g, 256, 0, stream>>>((const unsigned short*)(W + o_abf), Wo1,
                                              W + o_part, 512, 1536, 12288, 1536);
        reduce_bias_act<<<3072, 256, 0, stream>>>(W + o_part, bo1, W + o_h1, 512 * 1536, 1536, 8, 1);
    }
    // out = h1 @ Wo2 + bo2 (f32 split-K=16)
    {
        dim3 g(3, 8, 16);
        gemm_sk<0><<<g, 256, 0, stream>>>(W + o_h1, Wo2, W + o_part, 512, 192, 1536, 96);
        reduce_bias_act<<<384, 256, 0, stream>>>(W + o_part, bo2, (float*)d_out, 512 * 192, 192, 16, 0);
    }
}

// Round 21
// 253.968 us; speedup vs baseline: 1.2073x; 1.0035x over previous
//
#include <hip/hip_runtime.h>
#include <math.h>

#define DEVINL __device__ __forceinline__

DEVINL float sigm(float x) { return 1.0f / (1.0f + __expf(-x)); }
DEVINL float tanh_fast(float x) { return 2.0f / (1.0f + __expf(-2.0f * x)) - 1.0f; }
DEVINL unsigned short bf16rne(float f) {
    unsigned u = __float_as_uint(f);
    return (unsigned short)((u + 0x7FFFu + ((u >> 16) & 1u)) >> 16);
}

typedef __attribute__((ext_vector_type(8))) short bf16x8;
typedef __attribute__((ext_vector_type(4))) float f32x4;

// ---------------------------------------------------------------------------
// Generic small GEMM, K-unrolled x4 (R11-verified)
// ---------------------------------------------------------------------------
__global__ void gemm_small(const float* __restrict__ A, const float* __restrict__ W,
                           const float* __restrict__ bias, float* __restrict__ C,
                           int M, int N, int K, int act, int vgroup)
{
    int idx = blockIdx.x * blockDim.x + threadIdx.x;
    if (idx >= M * N) return;
    int m = idx / N, n = idx - m * N;
    int am = m;
    if (vgroup) { int g = m / vgroup; am = g * (vgroup + 1) + (m - g * vgroup); }
    const float* a = A + (size_t)am * K;
    const float* w = W + n;
    float acc = bias ? bias[n] : 0.0f;
    for (int k = 0; k < K; k += 4) {
        float4 av = *(const float4*)&a[k];
        float w0 = w[(size_t)k * N];
        float w1 = w[(size_t)(k + 1) * N];
        float w2 = w[(size_t)(k + 2) * N];
        float w3 = w[(size_t)(k + 3) * N];
        acc = fmaf(av.x, w0, acc);
        acc = fmaf(av.y, w1, acc);
        acc = fmaf(av.z, w2, acc);
        acc = fmaf(av.w, w3, acc);
    }
    if (act == 1) acc = fmaxf(acc, 0.0f);
    else if (act == 2) acc = tanh_fast(acc);
    C[idx] = acc;
}

// ---------------------------------------------------------------------------
// Dual-output small GEMM (R12-verified): C1 = A@W1, C2 = A@W2, A read once.
// ---------------------------------------------------------------------------
__global__ void gemm_small_dual(const float* __restrict__ A,
    const float* __restrict__ W1, const float* __restrict__ W2,
    float* __restrict__ C1, float* __restrict__ C2, int M, int N, int K)
{
    int idx = blockIdx.x * blockDim.x + threadIdx.x;
    if (idx >= M * N) return;
    int m = idx / N, n = idx - m * N;
    const float* a = A + (size_t)m * K;
    const float* w1 = W1 + n;
    const float* w2 = W2 + n;
    float acc1 = 0.0f, acc2 = 0.0f;
    for (int k = 0; k < K; k += 4) {
        float4 av = *(const float4*)&a[k];
        float p0 = w1[(size_t)k * N],       q0 = w2[(size_t)k * N];
        float p1 = w1[(size_t)(k + 1) * N], q1 = w2[(size_t)(k + 1) * N];
        float p2 = w1[(size_t)(k + 2) * N], q2 = w2[(size_t)(k + 2) * N];
        float p3 = w1[(size_t)(k + 3) * N], q3 = w2[(size_t)(k + 3) * N];
        acc1 = fmaf(av.x, p0, acc1); acc2 = fmaf(av.x, q0, acc2);
        acc1 = fmaf(av.y, p1, acc1); acc2 = fmaf(av.y, q1, acc2);
        acc1 = fmaf(av.z, p2, acc1); acc2 = fmaf(av.z, q2, acc2);
        acc1 = fmaf(av.w, p3, acc1); acc2 = fmaf(av.w, q3, acc2);
    }
    C1[idx] = acc1;
    C2[idx] = acc2;
}

// ---------------------------------------------------------------------------
// Wave-parallel GRU (R6-verified)
// ---------------------------------------------------------------------------
__global__ __launch_bounds__(256) void gru_wave(const float* __restrict__ glu,
    const float* __restrict__ timev, const float* __restrict__ Wx,
    const float* __restrict__ Wh, const float* __restrict__ bb,
    float* __restrict__ out)
{
    __shared__ float sWh[768], sWx[96], sb[48];
    int tid = threadIdx.x;
    for (int i = tid; i < 768; i += 256) sWh[i] = Wh[i];
    if (tid < 96) sWx[tid] = Wx[tid];
    if (tid < 48) sb[tid] = bb[tid];
    __syncthreads();
    int j = tid & 15;
    int seq = blockIdx.x * 16 + (tid >> 4);
    int gbase = (tid & 63) & 0x30;
    float whz[16], whr[16], whn[16];
#pragma unroll
    for (int i = 0; i < 16; ++i) {
        whz[i] = sWh[i * 48 + j];
        whr[i] = sWh[i * 48 + 16 + j];
        whn[i] = sWh[i * 48 + 32 + j];
    }
    float wxz0 = sWx[j],      wxr0 = sWx[16 + j], wxn0 = sWx[32 + j];
    float wxz1 = sWx[48 + j], wxr1 = sWx[64 + j], wxn1 = sWx[80 + j];
    float bz = sb[j], br = sb[16 + j], bn = sb[32 + j];
    const float* gp = glu + (size_t)seq * 48;
    const float* tp = timev + (size_t)seq * 48;
    float h = 0.0f;
    for (int t = 0; t < 48; ++t) {
        float gl = gp[t], tm = tp[t];
        float gz = fmaf(gl, wxz0, fmaf(tm, wxz1, bz));
        float gr = fmaf(gl, wxr0, fmaf(tm, wxr1, br));
        float gn = fmaf(gl, wxn0, fmaf(tm, wxn1, bn));
        float ghn = 0.0f;
#pragma unroll
        for (int i = 0; i < 16; ++i) {
            float hb = __shfl(h, gbase + i, 64);
            gz = fmaf(hb, whz[i], gz);
            gr = fmaf(hb, whr[i], gr);
            ghn = fmaf(hb, whn[i], ghn);
        }
        float z = sigm(gz), r = sigm(gr);
        float n = tanh_fast(gn + r * ghn);
        h = (1.0f - z) * n + z * h;
    }
    out[(size_t)seq * 16 + j] = h;
}

// ---------------------------------------------------------------------------
// glu attn_enc (per batch) -> patient_rep with static concat
// ---------------------------------------------------------------------------
__global__ __launch_bounds__(256) void glu_attn(const float* __restrict__ hg,
    const float* __restrict__ Wq, const float* __restrict__ Wk,
    const float* __restrict__ s2, float* __restrict__ patient)
{
    int b = blockIdx.x, tid = threadIdx.x;
    __shared__ float sh[512], sq[256], sk[256], ss[256];
    sh[tid] = hg[(size_t)b * 512 + tid];
    sh[256 + tid] = hg[(size_t)b * 512 + 256 + tid];
    __syncthreads();
    {
        int p = tid >> 4, j = tid & 15;
        float aq = 0.0f, ak = 0.0f;
        for (int i = 0; i < 32; ++i) {
            float hv = sh[p * 32 + i];
            aq = fmaf(hv, Wq[i * 16 + j], aq);
            ak = fmaf(hv, Wk[i * 16 + j], ak);
        }
        sq[tid] = aq; sk[tid] = ak;
    }
    __syncthreads();
    {
        int p = tid >> 4, pk = tid & 15;
        float a = 0.0f;
        for (int j = 0; j < 16; ++j) a = fmaf(sq[p * 16 + j], sk[pk * 16 + j], a);
        ss[tid] = a * 0.25f;
    }
    __syncthreads();
    if (tid < 16) {
        float mx = -1e30f;
        for (int k = 0; k < 16; ++k) mx = fmaxf(mx, ss[tid * 16 + k]);
        float sum = 0.0f;
        for (int k = 0; k < 16; ++k) { float e = __expf(ss[tid * 16 + k] - mx); ss[tid * 16 + k] = e; sum += e; }
        float inv = 1.0f / sum;
        for (int k = 0; k < 16; ++k) ss[tid * 16 + k] *= inv;
    }
    __syncthreads();
    for (int o = tid; o < 512; o += 256) {
        int p = o >> 5, c = o & 31;
        float acc = 0.0f;
        for (int pk = 0; pk < 16; ++pk) acc = fmaf(ss[p * 16 + pk], sh[pk * 32 + c], acc);
        patient[((size_t)b * 16 + p) * 64 + c] = acc;
        patient[((size_t)b * 16 + p) * 64 + 32 + c] = s2[(size_t)b * 32 + c];
    }
}

// ---------------------------------------------------------------------------
// med attn_enc (per batch)
// ---------------------------------------------------------------------------
__global__ __launch_bounds__(256) void med_attn(const float* __restrict__ hm,
    const float* __restrict__ Wq, const float* __restrict__ Wk,
    float* __restrict__ med_rep)
{
    int b = blockIdx.x, tid = threadIdx.x;
    __shared__ float sh[960], sq[480], sk[480], ss[225];
    for (int i = tid; i < 960; i += 256) sh[i] = hm[(size_t)b * 960 + i];
    __syncthreads();
    for (int o = tid; o < 480; o += 256) {
        int p = o >> 5, j = o & 31;
        float aq = 0.0f, ak = 0.0f;
        for (int i = 0; i < 64; ++i) {
            float hv = sh[p * 64 + i];
            aq = fmaf(hv, Wq[i * 32 + j], aq);
            ak = fmaf(hv, Wk[i * 32 + j], ak);
        }
        sq[o] = aq; sk[o] = ak;
    }
    __syncthreads();
    if (tid < 225) {
        int p = tid / 15, pk = tid - p * 15;
        float a = 0.0f;
        for (int j = 0; j < 32; ++j) a = fmaf(sq[p * 32 + j], sk[pk * 32 + j], a);
        ss[tid] = a * 0.17677669529663687f;
    }
    __syncthreads();
    if (tid < 15) {
        float mx = -1e30f;
        for (int k = 0; k < 15; ++k) mx = fmaxf(mx, ss[tid * 15 + k]);
        float sum = 0.0f;
        for (int k = 0; k < 15; ++k) { float e = __expf(ss[tid * 15 + k] - mx); ss[tid * 15 + k] = e; sum += e; }
        float inv = 1.0f / sum;
        for (int k = 0; k < 15; ++k) ss[tid * 15 + k] *= inv;
    }
    __syncthreads();
    for (int o = tid; o < 960; o += 256) {
        int p = o >> 6, c = o & 63;
        float acc = 0.0f;
        for (int pk = 0; pk < 15; ++pk) acc = fmaf(ss[p * 15 + pk], sh[pk * 64 + c], acc);
        med_rep[(size_t)b * 960 + o] = acc;
    }
}

// ---------------------------------------------------------------------------
// drug_mem[192,64]
// ---------------------------------------------------------------------------
__global__ void drugmem_kernel(const float* __restrict__ ehr, const float* __restrict__ tadj,
    const float* __restrict__ ddi,
    const float* __restrict__ Wl1, const float* __restrict__ bl1,
    const float* __restrict__ Wl2, const float* __restrict__ bl2,
    const float* __restrict__ Wl3, const float* __restrict__ bl3,
    float* __restrict__ dm)
{
    int idx = blockIdx.x * 256 + threadIdx.x;
    if (idx >= 192 * 64) return;
    int m = idx >> 6, n = idx & 63;
    float acc = bl1[n] + bl2[n] - bl3[n];
    for (int k = 0; k < 192; ++k) {
        acc = fmaf(ehr[m * 192 + k], Wl1[k * 64 + n], acc);
        acc = fmaf(tadj[m * 192 + k], Wl2[k * 64 + n], acc);
        acc = fmaf(-ddi[m * 192 + k], Wl3[k * 64 + n], acc);
    }
    dm[idx] = acc;
}

// ---------------------------------------------------------------------------
// MHA-1 (per batch). sq/sk padded to stride 68.
// ---------------------------------------------------------------------------
__global__ __launch_bounds__(256) void mha1_attn(const float* __restrict__ qh1,
    const float* __restrict__ kh1, const float* __restrict__ vh1,
    const float* __restrict__ Wo, float* __restrict__ Een)
{
    int b = blockIdx.x, tid = threadIdx.x;
    __shared__ float sq[1020], sk[1088], sv[1024], ss[960], so[960];
    for (int i = tid; i < 960; i += 256) sq[(i >> 6) * 68 + (i & 63)] = qh1[(size_t)b * 960 + i];
    for (int i = tid; i < 1024; i += 256) {
        sk[(i >> 6) * 68 + (i & 63)] = kh1[(size_t)b * 1024 + i];
        sv[i] = vh1[(size_t)b * 1024 + i];
    }
    __syncthreads();
    for (int o = tid; o < 960; o += 256) {
        int hh = o / 240, rem = o - hh * 240, q = rem >> 4, k = rem & 15;
        float a = 0.0f;
        for (int d = 0; d < 16; ++d) a = fmaf(sq[q * 68 + hh * 16 + d], sk[k * 68 + hh * 16 + d], a);
        ss[o] = a * 0.25f;
    }
    __syncthreads();
    if (tid < 60) {
        int base = tid * 16;
        float mx = -1e30f;
        for (int k = 0; k < 16; ++k) mx = fmaxf(mx, ss[base + k]);
        float sum = 0.0f;
        for (int k = 0; k < 16; ++k) { float e = __expf(ss[base + k] - mx); ss[base + k] = e; sum += e; }
        float inv = 1.0f / sum;
        for (int k = 0; k < 16; ++k) ss[base + k] *= inv;
    }
    __syncthreads();
    for (int o = tid; o < 960; o += 256) {
        int q = o >> 6, j = o & 63, hh = j >> 4;
        float a = 0.0f;
        for (int k = 0; k < 16; ++k) a = fmaf(ss[hh * 240 + q * 16 + k], sv[k * 64 + j], a);
        so[o] = a;
    }
    __syncthreads();
    for (int o = tid; o < 960; o += 256) {
        int q = o >> 6, c = o & 63;
        float a = 0.0f;
        for (int j = 0; j < 64; ++j) a = fmaf(so[q * 64 + j], Wo[j * 64 + c], a);
        Een[(size_t)b * 960 + o] = a;
    }
}

// ---------------------------------------------------------------------------
// MHA-2 v2 (R8-verified): block per (batch, q-chunk); stride-68 K; no Wo.
// ---------------------------------------------------------------------------
__global__ __launch_bounds__(256) void mha2_attn2(const float* __restrict__ qh2,
    const float* __restrict__ kh2, const float* __restrict__ vh2,
    float* __restrict__ so_all)
{
    int b = blockIdx.x >> 2, q0 = (blockIdx.x & 3) * 48;
    int tid = threadIdx.x;
    __shared__ float skp[1020], sv[960], ss[2880];
    for (int i = tid; i < 960; i += 256) {
        skp[(i >> 6) * 68 + (i & 63)] = kh2[(size_t)b * 960 + i];
        sv[i] = vh2[(size_t)b * 960 + i];
    }
    __syncthreads();
    for (int o = tid; o < 2880; o += 256) {
        int hh = o / 720, rem = o - hh * 720, q = rem / 15, k = rem - q * 15;
        const float* qp = qh2 + (size_t)(q0 + q) * 64 + hh * 16;
        float a = 0.0f;
        for (int d = 0; d < 16; ++d) a = fmaf(qp[d], skp[k * 68 + hh * 16 + d], a);
        ss[o] = a * 0.25f;
    }
    __syncthreads();
    if (tid < 192) {
        int hh = tid / 48, q = tid - hh * 48;
        int base = hh * 720 + q * 15;
        float mx = -1e30f;
        for (int k = 0; k < 15; ++k) mx = fmaxf(mx, ss[base + k]);
        float sum = 0.0f;
        for (int k = 0; k < 15; ++k) { float e = __expf(ss[base + k] - mx); ss[base + k] = e; sum += e; }
        float inv = 1.0f / sum;
        for (int k = 0; k < 15; ++k) ss[base + k] *= inv;
    }
    __syncthreads();
    for (int o = tid; o < 3072; o += 256) {
        int q = o >> 6, j = o & 63, hh = j >> 4;
        float a = 0.0f;
        for (int k = 0; k < 15; ++k) a = fmaf(ss[hh * 720 + q * 15 + k], sv[k * 64 + j], a);
        so_all[((size_t)b * 192 + q0 + q) * 64 + j] = a;
    }
}

// ---------------------------------------------------------------------------
// Abf = bf16(relu(so[98304,64] @ Wo[64,64])), f32 math, fused epilogue.
// ---------------------------------------------------------------------------
__global__ __launch_bounds__(256) void gemm64_relu_bf16(const float* __restrict__ A,
    const float* __restrict__ B, unsigned short* __restrict__ Obf)
{
    __shared__ float As[64 * 20];
    __shared__ float Bs[16 * 64];
    int tid = threadIdx.x;
    int m0 = blockIdx.x * 64;
    float acc[4][4] = {};
    int arow = tid >> 2, akq = (tid & 3) << 2;
    int brow = tid >> 4, bnq = (tid & 15) << 2;
    int tm0 = (tid >> 4) << 2, tn0 = (tid & 15) << 2;
    for (int kt = 0; kt < 64; kt += 16) {
        float4 av = *(const float4*)&A[(size_t)(m0 + arow) * 64 + kt + akq];
        *(float4*)&As[arow * 20 + akq] = av;
        float4 bv = *(const float4*)&B[(size_t)(kt + brow) * 64 + bnq];
        *(float4*)&Bs[brow * 64 + bnq] = bv;
        __syncthreads();
#pragma unroll
        for (int kk = 0; kk < 16; ++kk) {
            float4 b4 = *(const float4*)&Bs[kk * 64 + tn0];
            float a0 = As[(tm0 + 0) * 20 + kk];
            float a1 = As[(tm0 + 1) * 20 + kk];
            float a2 = As[(tm0 + 2) * 20 + kk];
            float a3 = As[(tm0 + 3) * 20 + kk];
            acc[0][0] = fmaf(a0, b4.x, acc[0][0]); acc[0][1] = fmaf(a0, b4.y, acc[0][1]);
            acc[0][2] = fmaf(a0, b4.z, acc[0][2]); acc[0][3] = fmaf(a0, b4.w, acc[0][3]);
            acc[1][0] = fmaf(a1, b4.x, acc[1][0]); acc[1][1] = fmaf(a1, b4.y, acc[1][1]);
            acc[1][2] = fmaf(a1, b4.z, acc[1][2]); acc[1][3] = fmaf(a1, b4.w, acc[1][3]);
            acc[2][0] = fmaf(a2, b4.x, acc[2][0]); acc[2][1] = fmaf(a2, b4.y, acc[2][1]);
            acc[2][2] = fmaf(a2, b4.z, acc[2][2]); acc[2][3] = fmaf(a2, b4.w, acc[2][3]);
            acc[3][0] = fmaf(a3, b4.x, acc[3][0]); acc[3][1] = fmaf(a3, b4.y, acc[3][1]);
            acc[3][2] = fmaf(a3, b4.z, acc[3][2]); acc[3][3] = fmaf(a3, b4.w, acc[3][3]);
        }
        __syncthreads();
    }
#pragma unroll
    for (int i = 0; i < 4; ++i) {
        unsigned r0 = (unsigned)bf16rne(fmaxf(acc[i][0], 0.f)) | ((unsigned)bf16rne(fmaxf(acc[i][1], 0.f)) << 16);
        unsigned r1 = (unsigned)bf16rne(fmaxf(acc[i][2], 0.f)) | ((unsigned)bf16rne(fmaxf(acc[i][3], 0.f)) << 16);
        uint2 v = { r0, r1 };
        *(uint2*)&Obf[(size_t)(m0 + tm0 + i) * 64 + tn0] = v;
    }
}

// ---------------------------------------------------------------------------
// MFMA bf16 split-K GEMM — EXACT R12/R19 kernel (twice verified: 255us /
// 254.8us total, 71us dispatch). 128m x 64n, BK=64, sk=8, conflict-free
// scalar B staging. The 64x64@z=8 variant is permanently abandoned (0/3,
// incl. an abort adjacent to a healthy pass). This banks the best state.
// ---------------------------------------------------------------------------
__global__ __launch_bounds__(256) void gemm_mfma_bf16(
    const unsigned short* __restrict__ Abf, const float* __restrict__ B,
    float* __restrict__ Cp, int M, int N, int K, int klen)
{
    __shared__ unsigned short As[128 * 64];   // 16 KB, XOR-swizzled rows
    __shared__ unsigned short Bs[64 * 64];    // 8 KB, [n][k] XOR-swizzled
    int tid = threadIdx.x;
    int lane = tid & 63, w = tid >> 6;        // 4 waves, wave w owns m-rows [w*32, w*32+32)
    int n0 = blockIdx.x * 64, m0 = blockIdx.y * 128;
    int kbase0 = blockIdx.z * klen;
    f32x4 acc[2][4] = {};

    int bn = tid & 63, bkc = (tid >> 6) * 16;
    for (int kt = 0; kt < klen; kt += 64) {
        int kb = kbase0 + kt;
        // stage A: 128 rows x 64 k = 1024 chunks of 16B; 4 per thread
#pragma unroll
        for (int c = 0; c < 4; ++c) {
            int ch = tid + c * 256;
            int row = ch >> 3, kc0 = (ch & 7) << 3;
            uint4 v = *(const uint4*)&Abf[(size_t)(m0 + row) * K + kb + kc0];
            int bo = ((row << 7) + (kc0 << 1)) ^ ((row & 7) << 4);
            *(uint4*)((char*)As + bo) = v;
        }
        // stage B transposed ([n][k]) with f32->bf16 convert
        {
            const float* bp = &B[(size_t)(kb + bkc) * N + n0 + bn];
#pragma unroll
            for (int j = 0; j < 16; j += 2) {
                float f0 = bp[(size_t)j * N];
                float f1 = bp[(size_t)(j + 1) * N];
                unsigned u = (unsigned)bf16rne(f0) | ((unsigned)bf16rne(f1) << 16);
                int k = bkc + j;
                int bo = ((bn << 7) + (k << 1)) ^ ((bn & 7) << 4);
                *(unsigned*)((char*)Bs + bo) = u;
            }
        }
        __syncthreads();
#pragma unroll
        for (int kk = 0; kk < 64; kk += 32) {
            int kb2 = (kk + ((lane >> 4) << 3)) << 1;
            bf16x8 af[2], bfg[4];
#pragma unroll
            for (int fm = 0; fm < 2; ++fm) {
                int row = (w << 5) + (fm << 4) + (lane & 15);
                af[fm] = *(const bf16x8*)((const char*)As + (((row << 7) + kb2) ^ ((row & 7) << 4)));
            }
#pragma unroll
            for (int fn = 0; fn < 4; ++fn) {
                int col = (fn << 4) + (lane & 15);
                bfg[fn] = *(const bf16x8*)((const char*)Bs + (((col << 7) + kb2) ^ ((col & 7) << 4)));
            }
#pragma unroll
            for (int fm = 0; fm < 2; ++fm)
#pragma unroll
                for (int fn = 0; fn < 4; ++fn)
                    acc[fm][fn] = __builtin_amdgcn_mfma_f32_16x16x32_bf16(af[fm], bfg[fn], acc[fm][fn], 0, 0, 0);
        }
        __syncthreads();
    }
    float* cp = Cp + (size_t)blockIdx.z * M * N;
#pragma unroll
    for (int fm = 0; fm < 2; ++fm)
#pragma unroll
        for (int fn = 0; fn < 4; ++fn) {
            int row = m0 + (w << 5) + (fm << 4) + ((lane >> 4) << 2);
            int col = n0 + (fn << 4) + (lane & 15);
#pragma unroll
            for (int r = 0; r < 4; ++r)
                cp[(size_t)(row + r) * N + col] = acc[fm][fn][r];
        }
}

// ---------------------------------------------------------------------------
// Split-K tiled f32 GEMM
// ---------------------------------------------------------------------------
template <int RELU_A>
__global__ __launch_bounds__(256) void gemm_sk(const float* __restrict__ A,
    const float* __restrict__ B, float* __restrict__ Cp,
    int M, int N, int K, int klen)
{
    __shared__ float As[64 * 20];
    __shared__ float Bs[16 * 64];
    int tid = threadIdx.x;
    int n0 = blockIdx.x * 64, m0 = blockIdx.y * 64;
    int bs = blockIdx.z;
    int kbase0 = bs * klen;
    float acc[4][4] = {};
    int arow = tid >> 2, akq = (tid & 3) << 2;
    int brow = tid >> 4, bnq = (tid & 15) << 2;
    int tm0 = (tid >> 4) << 2, tn0 = (tid & 15) << 2;
    for (int kt = 0; kt < klen; kt += 16) {
        int kb = kbase0 + kt;
        float4 av = *(const float4*)&A[(size_t)(m0 + arow) * K + kb + akq];
        if (RELU_A) {
            av.x = fmaxf(av.x, 0.0f); av.y = fmaxf(av.y, 0.0f);
            av.z = fmaxf(av.z, 0.0f); av.w = fmaxf(av.w, 0.0f);
        }
        *(float4*)&As[arow * 20 + akq] = av;
        float4 bv = *(const float4*)&B[(size_t)(kb + brow) * N + n0 + bnq];
        *(float4*)&Bs[brow * 64 + bnq] = bv;
        __syncthreads();
#pragma unroll
        for (int kk = 0; kk < 16; ++kk) {
            float4 b4 = *(const float4*)&Bs[kk * 64 + tn0];
            float a0 = As[(tm0 + 0) * 20 + kk];
            float a1 = As[(tm0 + 1) * 20 + kk];
            float a2 = As[(tm0 + 2) * 20 + kk];
            float a3 = As[(tm0 + 3) * 20 + kk];
            acc[0][0] = fmaf(a0, b4.x, acc[0][0]); acc[0][1] = fmaf(a0, b4.y, acc[0][1]);
            acc[0][2] = fmaf(a0, b4.z, acc[0][2]); acc[0][3] = fmaf(a0, b4.w, acc[0][3]);
            acc[1][0] = fmaf(a1, b4.x, acc[1][0]); acc[1][1] = fmaf(a1, b4.y, acc[1][1]);
            acc[1][2] = fmaf(a1, b4.z, acc[1][2]); acc[1][3] = fmaf(a1, b4.w, acc[1][3]);
            acc[2][0] = fmaf(a2, b4.x, acc[2][0]); acc[2][1] = fmaf(a2, b4.y, acc[2][1]);
            acc[2][2] = fmaf(a2, b4.z, acc[2][2]); acc[2][3] = fmaf(a2, b4.w, acc[2][3]);
            acc[3][0] = fmaf(a3, b4.x, acc[3][0]); acc[3][1] = fmaf(a3, b4.y, acc[3][1]);
            acc[3][2] = fmaf(a3, b4.z, acc[3][2]); acc[3][3] = fmaf(a3, b4.w, acc[3][3]);
        }
        __syncthreads();
    }
    float* cp = Cp + (size_t)bs * M * N;
#pragma unroll
    for (int i = 0; i < 4; ++i)
#pragma unroll
        for (int j = 0; j < 4; ++j)
            cp[(size_t)(m0 + tm0 + i) * N + n0 + tn0 + j] = acc[i][j];
}

__global__ void reduce_bias_act(const float* __restrict__ part, const float* __restrict__ bias,
                                float* __restrict__ out, int MN, int N, int S, int relu)
{
    int idx = blockIdx.x * 256 + threadIdx.x;
    if (idx >= MN) return;
    float a = bias[idx % N];
    for (int s = 0; s < S; ++s) a += part[(size_t)s * MN + idx];
    if (relu) a = fmaxf(a, 0.0f);
    out[idx] = a;
}

// ---------------------------------------------------------------------------
// Workspace: 44.3 MB (proven). MFMA sk=8 partials = 8x786432 = Region B.
// ---------------------------------------------------------------------------
extern "C" void kernel_launch(void* const* d_in, const int* in_sizes, int n_in,
                              void* d_out, int out_size, void* d_ws, size_t ws_size,
                              hipStream_t stream)
{
    const float* lab    = (const float*)d_in[0];
    const float* glu    = (const float*)d_in[1];
    const float* timev  = (const float*)d_in[2];
    const float* med    = (const float*)d_in[3];
    const float* ehr    = (const float*)d_in[4];
    const float* ddi    = (const float*)d_in[5];
    const float* tadj   = (const float*)d_in[6];
    const float* Ws1    = (const float*)d_in[7];
    const float* bs1    = (const float*)d_in[8];
    const float* Ws2    = (const float*)d_in[9];
    const float* bs2    = (const float*)d_in[10];
    const float* Wl1    = (const float*)d_in[11];
    const float* bl1    = (const float*)d_in[12];
    const float* Wl2    = (const float*)d_in[13];
    const float* bl2    = (const float*)d_in[14];
    const float* Wl3    = (const float*)d_in[15];
    const float* bl3    = (const float*)d_in[16];
    const float* Wm1    = (const float*)d_in[17];
    const float* bm1    = (const float*)d_in[18];
    const float* Wmq    = (const float*)d_in[19];
    const float* Wmk    = (const float*)d_in[20];
    const float* Wg1    = (const float*)d_in[21];
    const float* bg1    = (const float*)d_in[22];
    const float* Wgq    = (const float*)d_in[23];
    const float* Wgk    = (const float*)d_in[24];
    const float* gWx    = (const float*)d_in[25];
    const float* gWh    = (const float*)d_in[26];
    const float* gb     = (const float*)d_in[27];
    const float* m1Wq   = (const float*)d_in[28];
    const float* m1Wk   = (const float*)d_in[29];
    const float* m1Wv   = (const float*)d_in[30];
    const float* m1Wo   = (const float*)d_in[31];
    const float* m2Wq   = (const float*)d_in[32];
    const float* m2Wk   = (const float*)d_in[33];
    const float* m2Wv   = (const float*)d_in[34];
    const float* m2Wo   = (const float*)d_in[35];
    const float* Wo1    = (const float*)d_in[36];
    const float* bo1    = (const float*)d_in[37];
    const float* Wo2    = (const float*)d_in[38];
    const float* bo2    = (const float*)d_in[39];

    float* W = (float*)d_ws;
    size_t off = 0;
    auto alloc = [&](size_t n) { size_t r = off; off += (n + 3) & ~(size_t)3; return r; };
    // ---- Region A ----
    size_t o_s1      = alloc(512 * 64);
    size_t o_s2      = alloc(512 * 32);
    size_t o_gluenc  = alloc(8192 * 16);
    size_t o_hg      = alloc(8192 * 32);
    size_t o_patient = alloc(8192 * 64);
    size_t o_medh    = alloc(7680 * 64);
    size_t o_medrep  = alloc(7680 * 64);
    size_t o_dm      = alloc(192 * 64);
    size_t o_qh2s    = alloc(192 * 64);
    size_t o_qh1     = alloc(7680 * 64);
    size_t o_kh1     = alloc(8192 * 64);
    size_t o_vh1     = alloc(8192 * 64);
    size_t o_Een     = alloc(7680 * 64);
    size_t o_kh2 = o_medh;      // aliases dead-after-mha1 buffers
    size_t o_vh2 = o_qh1;
    size_t o_abf = 0;           // Abf aliases Region A start after mha2
    // ---- Regions B, C ----
    size_t o_so      = alloc((size_t)512 * 12288);   // attention output (pre-Wo)
    size_t o_h1      = alloc((size_t)512 * 1536);
    size_t o_part    = o_so;    // split-K partials alias region B

    // static path
    {
        dim3 g(1, 8, 4);
        gemm_sk<0><<<g, 256, 0, stream>>>(lab, Ws1, W + o_part, 512, 64, 256, 64);
        reduce_bias_act<<<128, 256, 0, stream>>>(W + o_part, bs1, W + o_s1, 512 * 64, 64, 4, 1);
    }
    gemm_small<<<64, 256, 0, stream>>>(W + o_s1, Ws2, bs2, W + o_s2, 512, 32, 64, 1, 0);
    // GRU (wave-parallel)
    gru_wave<<<512, 256, 0, stream>>>(glu, timev, gWx, gWh, gb, W + o_gluenc);
    // glu attn encoder -> patient_rep
    gemm_small<<<1024, 256, 0, stream>>>(W + o_gluenc, Wg1, bg1, W + o_hg, 8192, 32, 16, 2, 0);
    glu_attn<<<512, 256, 0, stream>>>(W + o_hg, Wgq, Wgk, W + o_s2, W + o_patient);
    // med attn encoder
    gemm_small<<<1920, 256, 0, stream>>>(med, Wm1, bm1, W + o_medh, 7680, 64, 192, 2, 15);
    med_attn<<<512, 256, 0, stream>>>(W + o_medh, Wmq, Wmk, W + o_medrep);
    // drug memory + shared qh2
    drugmem_kernel<<<48, 256, 0, stream>>>(ehr, tadj, ddi, Wl1, bl1, Wl2, bl2, Wl3, bl3, W + o_dm);
    gemm_small<<<48, 256, 0, stream>>>(W + o_dm, m2Wq, nullptr, W + o_qh2s, 192, 64, 64, 0, 0);
    // MHA-1 (K/V fused)
    gemm_small<<<1920, 256, 0, stream>>>(W + o_medrep, m1Wq, nullptr, W + o_qh1, 7680, 64, 64, 0, 0);
    gemm_small_dual<<<2048, 256, 0, stream>>>(W + o_patient, m1Wk, m1Wv,
                                              W + o_kh1, W + o_vh1, 8192, 64, 64);
    mha1_attn<<<512, 256, 0, stream>>>(W + o_qh1, W + o_kh1, W + o_vh1, m1Wo, W + o_Een);
    // MHA-2 (K/V fused; no Wo epilogue)
    gemm_small_dual<<<1920, 256, 0, stream>>>(W + o_Een, m2Wk, m2Wv,
                                              W + o_kh2, W + o_vh2, 7680, 64, 64);
    mha2_attn2<<<2048, 256, 0, stream>>>(W + o_qh2s, W + o_kh2, W + o_vh2, W + o_so);
    // Abf = bf16(relu(so @ m2_Wo))
    gemm64_relu_bf16<<<1536, 256, 0, stream>>>(W + o_so, m2Wo, (unsigned short*)(W + o_abf));
    // h1 = relu(Abf @ bf16(Wo1) + bo1), MFMA 128x64 tile, split-K=8
    {
        dim3 g(24, 4, 8);
        gemm_mfma_bf16<<<g, 256, 0, stream>>>((const unsigned short*)(W + o_abf), Wo1,
                                              W + o_part, 512, 1536, 12288, 1536);
        reduce_bias_act<<<3072, 256, 0, stream>>>(W + o_part, bo1, W + o_h1, 512 * 1536, 1536, 8, 1);
    }
    // out = h1 @ Wo2 + bo2 (f32 split-K=16)
    {
        dim3 g(3, 8, 16);
        gemm_sk<0><<<g, 256, 0, stream>>>(W + o_h1, Wo2, W + o_part, 512, 192, 1536, 96);
        reduce_bias_act<<<384, 256, 0, stream>>>(W + o_part, bo2, (float*)d_out, 512 * 192, 192, 16, 0);
    }
}